// Round 12
// baseline (1214.501 us; speedup 1.0000x reference)
//
#include <hip/hip_runtime.h>
#include <hip/hip_bf16.h>
#include <stdint.h>

// ---------------------------------------------------------------------------
// PlanetoidSCN R10: all SpMMs as CSR-gather (zero atomics in feature space,
// zero big memsets) + split-bf16 MFMA GEMMs.
//
// ws = S1 | S2 | Ts = 256,000,000 B exactly (known-safe since R6).
// Live-range overlays:
//   Ts head   : Xb/Eb/Tb bit tables      (die before B2-gather writes Ts)
//   d_out     : CSR-L1 9.2M, CSR-L2 9.6M, CSR-B2 6.0M, Wt/We/Wtri splits 0.2M
//               (= 25.0 MB < 25.6 MB; all dead before L0-gather writes d_out)
//   S1 region : Xb2, CSR-L0, CSR-B1, Wn split  (after U-GEMM consumes H1)
// Order: bits -> CSR L1/L2/B2 + splits -> L1/L2 gathers -> H2/H1 GEMMs ->
//        B2 gather (Ts) -> U GEMM -> phase-B builds in S1 -> L0 gather(d_out)
//        -> H0 GEMM -> B1 gather-add.
// ---------------------------------------------------------------------------

typedef __attribute__((ext_vector_type(8))) short bf16x8;
typedef __attribute__((ext_vector_type(4))) float f32x4;

__device__ __forceinline__ short f2bf(float x) {
    __hip_bfloat16 h = __float2bfloat16(x);
    return *reinterpret_cast<short*>(&h);
}
__device__ __forceinline__ float bf2f(short s) {
    __hip_bfloat16 h = *reinterpret_cast<__hip_bfloat16*>(&s);
    return __bfloat162float(h);
}

__global__ __launch_bounds__(256) void k_bits_node(const float* __restrict__ X,
        ulonglong2* __restrict__ bits, int n)
{
    int wid = (blockIdx.x * 256 + threadIdx.x) >> 6;
    int lane = threadIdx.x & 63;
    if (wid >= n) return;
    const float* row = X + (size_t)wid * 128;
    unsigned long long m0 = __ballot(row[lane] != 0.0f);
    unsigned long long m1 = __ballot(row[lane + 64] != 0.0f);
    if (lane == 0) { bits[wid].x = m0; bits[wid].y = m1; }
}

__global__ __launch_bounds__(256) void k_bits_edge(const int* __restrict__ idx,
        const ulonglong2* __restrict__ nb, ulonglong2* __restrict__ outb, int n)
{
    int e = blockIdx.x * 256 + threadIdx.x;
    if (e >= n) return;
    ulonglong2 a = nb[idx[2 * e]];
    ulonglong2 b = nb[idx[2 * e + 1]];
    ulonglong2 r; r.x = a.x & b.x; r.y = a.y & b.y;
    outb[e] = r;
}

__global__ __launch_bounds__(256) void k_bits_tri(const int* __restrict__ idx,
        const ulonglong2* __restrict__ nb, ulonglong2* __restrict__ outb, int n)
{
    int e = blockIdx.x * 256 + threadIdx.x;
    if (e >= n) return;
    ulonglong2 a = nb[idx[3 * e]];
    ulonglong2 b = nb[idx[3 * e + 1]];
    ulonglong2 c = nb[idx[3 * e + 2]];
    ulonglong2 r; r.x = a.x & b.x & c.x; r.y = a.y & b.y & c.y;
    outb[e] = r;
}

// ---------------- CSR build: histogram -> scan -> scatter -------------------

__global__ __launch_bounds__(256) void k_hist(const int* __restrict__ rows,
        int* __restrict__ rp, int nnz)
{
    int nz = blockIdx.x * 256 + threadIdx.x;
    if (nz >= nnz) return;
    atomicAdd(&rp[rows[nz] + 1], 1);
}

__global__ __launch_bounds__(256) void k_scan_block(int* __restrict__ a, int n,
        int* __restrict__ bsum)
{
    __shared__ int sm[256];
    int b = blockIdx.x, t = threadIdx.x;
    int g = b * 1024 + t * 4;
    int x0 = (g + 0 < n) ? a[g + 0] : 0;
    int x1 = (g + 1 < n) ? a[g + 1] : 0;
    int x2 = (g + 2 < n) ? a[g + 2] : 0;
    int x3 = (g + 3 < n) ? a[g + 3] : 0;
    int ts = x0 + x1 + x2 + x3;
    sm[t] = ts; __syncthreads();
    for (int ofs = 1; ofs < 256; ofs <<= 1) {
        int x = (t >= ofs) ? sm[t - ofs] : 0;
        __syncthreads();
        sm[t] += x;
        __syncthreads();
    }
    int excl = sm[t] - ts;
    if (g + 0 < n) a[g + 0] = excl + x0;
    if (g + 1 < n) a[g + 1] = excl + x0 + x1;
    if (g + 2 < n) a[g + 2] = excl + x0 + x1 + x2;
    if (g + 3 < n) a[g + 3] = excl + ts;
    if (t == 255) bsum[b] = sm[255];
}

__global__ __launch_bounds__(256) void k_scan_top(int* __restrict__ bsum, int nb)
{
    __shared__ int sm[256];
    int t = threadIdx.x;
    int v = (t < nb) ? bsum[t] : 0;
    sm[t] = v; __syncthreads();
    for (int ofs = 1; ofs < 256; ofs <<= 1) {
        int x = (t >= ofs) ? sm[t - ofs] : 0;
        __syncthreads();
        sm[t] += x;
        __syncthreads();
    }
    if (t < nb) bsum[t] = sm[t] - v;   // exclusive
}

// adds block offsets AND writes the rf (running-cursor) copy — no D2D memcpy.
__global__ __launch_bounds__(256) void k_scan_add_rf(int* __restrict__ a, int n,
        const int* __restrict__ bsum, int* __restrict__ rf)
{
    int g = blockIdx.x * 256 + threadIdx.x;
    if (g >= n) return;
    int v = a[g] + bsum[g >> 10];
    a[g] = v;
    rf[g] = v;
}

__global__ __launch_bounds__(256) void k_scatter(const int* __restrict__ rows,
        const int* __restrict__ cols, const float* __restrict__ vals,
        int* __restrict__ rf, int* __restrict__ colp, float* __restrict__ valp,
        int nnz, float scale)
{
    int nz = blockIdx.x * 256 + threadIdx.x;
    if (nz >= nnz) return;
    int r = rows[nz];
    int pos = atomicAdd(&rf[r], 1);
    colp[pos] = cols[nz];
    valp[pos] = vals[nz] * scale;
}

// One wave per row: S[r] = sum_i valp[i] * bits(colp[i]); lane owns 2 features.
__global__ __launch_bounds__(256) void k_gather_bin(const int* __restrict__ rp,
        const int* __restrict__ colp, const float* __restrict__ valp,
        const ulonglong2* __restrict__ bits, float* __restrict__ S, int nrows)
{
    int r = (blockIdx.x * 256 + threadIdx.x) >> 6;
    int lane = threadIdx.x & 63;
    if (r >= nrows) return;
    int s = rp[r], e = rp[r + 1];
    float a0 = 0.f, a1 = 0.f;
    const int sh = (lane * 2) & 63;
    const bool hi = lane >= 32;
    for (int i = s; i < e; ++i) {
        int c = colp[i];
        float v = valp[i];
        ulonglong2 m = bits[c];
        unsigned long long mm = hi ? m.y : m.x;
        if ((mm >> sh) & 1ull) a0 += v;
        if ((mm >> (sh + 1)) & 1ull) a1 += v;
    }
    *(float2*)(S + (size_t)r * 128 + lane * 2) = make_float2(a0, a1);
}

// One wave per row: Out[r] = sum valp[i] * X[colp[i]]  (writes all rows).
__global__ __launch_bounds__(256) void k_gather_write(const int* __restrict__ rp,
        const int* __restrict__ colp, const float* __restrict__ valp,
        const float* __restrict__ X, float* __restrict__ Out, int nrows)
{
    int r = (blockIdx.x * 256 + threadIdx.x) >> 6;
    int lane = threadIdx.x & 63;
    if (r >= nrows) return;
    int s = rp[r], e = rp[r + 1];
    float2 acc = make_float2(0.f, 0.f);
    for (int i = s; i < e; ++i) {
        int c = colp[i];
        float v = valp[i];
        float2 x = *(const float2*)(X + (size_t)c * 128 + lane * 2);
        acc.x += v * x.x;
        acc.y += v * x.y;
    }
    *(float2*)(Out + (size_t)r * 128 + lane * 2) = acc;
}

// One wave per row: Out[r] += sum valp[i] * X[colp[i]]  (skip empty rows).
__global__ __launch_bounds__(256) void k_gather_add(const int* __restrict__ rp,
        const int* __restrict__ colp, const float* __restrict__ valp,
        const float* __restrict__ X, float* __restrict__ Out, int nrows)
{
    int r = (blockIdx.x * 256 + threadIdx.x) >> 6;
    int lane = threadIdx.x & 63;
    if (r >= nrows) return;
    int s = rp[r], e = rp[r + 1];
    if (s == e) return;
    float2 acc = make_float2(0.f, 0.f);
    for (int i = s; i < e; ++i) {
        int c = colp[i];
        float v = valp[i];
        float2 x = *(const float2*)(X + (size_t)c * 128 + lane * 2);
        acc.x += v * x.x;
        acc.y += v * x.y;
    }
    float* o = Out + (size_t)r * 128 + lane * 2;
    float2 cur = *(float2*)o;
    cur.x += acc.x; cur.y += acc.y;
    *(float2*)o = cur;
}

// Split f32 W -> bf16 hi + bf16 lo (RNE both stages).
__global__ __launch_bounds__(256) void k_wsplit(const float* __restrict__ W,
        short* __restrict__ hi, short* __restrict__ lo, int n)
{
    int i = blockIdx.x * 256 + threadIdx.x;
    if (i >= n) return;
    float x = W[i];
    short h = f2bf(x);
    hi[i] = h;
    lo[i] = f2bf(x - bf2f(h));
}

// ---------------------------------------------------------------------------
// Split-bf16 MFMA GEMM: H = epi(S @ W^T + b). 4 waves, 64 rows x 128 cols.
// C ~= Shi*Whi + Shi*Wlo + Slo*Whi (f32 accum); |err| <~ 128*2^-18*|S||W|.
// ---------------------------------------------------------------------------
template<int PRELU, int ADDSRC>
__global__ __launch_bounds__(256) void k_gemm_mfma(const float* __restrict__ S,
        const short* __restrict__ Whi, const short* __restrict__ Wlo,
        const float* __restrict__ bias, const float* __restrict__ addsrc,
        const float* __restrict__ pw, float* __restrict__ H, int n_rows,
        float scale)
{
    __shared__ short Wh[128 * 136];
    __shared__ short Wl[128 * 136];
    const int t = threadIdx.x;

    const uint32_t* gh = (const uint32_t*)Whi;
    const uint32_t* gl = (const uint32_t*)Wlo;
    for (int i = t; i < 128 * 64; i += 256) {      // u32 = 2 bf16
        int r = i >> 6, cp = i & 63;
        *(uint32_t*)&Wh[r * 136 + cp * 2] = gh[r * 64 + cp];
        *(uint32_t*)&Wl[r * 136 + cp * 2] = gl[r * 64 + cp];
    }
    __syncthreads();

    const int wave = t >> 6, lane = t & 63;
    const int lm = lane & 15, kg = lane >> 4;
    const int band = blockIdx.x * 64 + wave * 16;
    const int row_a = band + lm;
    const bool arow_ok = row_a < n_rows;

    f32x4 acc[8];
#pragma unroll
    for (int ct = 0; ct < 8; ++ct) acc[ct] = (f32x4){0.f, 0.f, 0.f, 0.f};

    for (int ks = 0; ks < 4; ++ks) {
        const int k0 = ks * 32 + kg * 8;
        float a[8];
        if (arow_ok) {
            float4 v0 = *(const float4*)(S + (size_t)row_a * 128 + k0);
            float4 v1 = *(const float4*)(S + (size_t)row_a * 128 + k0 + 4);
            a[0]=v0.x; a[1]=v0.y; a[2]=v0.z; a[3]=v0.w;
            a[4]=v1.x; a[5]=v1.y; a[6]=v1.z; a[7]=v1.w;
        } else {
#pragma unroll
            for (int i = 0; i < 8; ++i) a[i] = 0.f;
        }
        bf16x8 ahi, alo;
#pragma unroll
        for (int i = 0; i < 8; ++i) {
            short h = f2bf(a[i]);
            ahi[i] = h;
            alo[i] = f2bf(a[i] - bf2f(h));
        }
#pragma unroll
        for (int ct = 0; ct < 8; ++ct) {
            const int brow = ct * 16 + lm;
            bf16x8 bhi = *(const bf16x8*)&Wh[brow * 136 + k0];
            bf16x8 blo = *(const bf16x8*)&Wl[brow * 136 + k0];
            acc[ct] = __builtin_amdgcn_mfma_f32_16x16x32_bf16(ahi, bhi, acc[ct], 0, 0, 0);
            acc[ct] = __builtin_amdgcn_mfma_f32_16x16x32_bf16(ahi, blo, acc[ct], 0, 0, 0);
            acc[ct] = __builtin_amdgcn_mfma_f32_16x16x32_bf16(alo, bhi, acc[ct], 0, 0, 0);
        }
    }

    const int r0 = band + kg * 4;
    float w = 0.f;
    if (PRELU) w = pw[0];
#pragma unroll
    for (int ct = 0; ct < 8; ++ct) {
        const int col = ct * 16 + lm;
        const float b = bias[col];
#pragma unroll
        for (int j = 0; j < 4; ++j) {
            const int row = r0 + j;
            if (row >= n_rows) continue;
            float x = acc[ct][j] + b;
            if (PRELU) x = x >= 0.f ? x : w * x;
            x *= scale;
            if (ADDSRC) x += addsrc[(size_t)row * 128 + col];
            H[(size_t)row * 128 + col] = x;
        }
    }
}

// helper to run one CSR build (6 enqueues, shared bsum)
static void build_csr(const int* rows, const int* cols, const float* vals,
                      int* rp, int* rf, int* colp, float* valp, int* bsum,
                      int nrows, int nnz, float scale, hipStream_t stream)
{
    dim3 blk(256);
    int n = nrows + 1;
    int nb = (n + 1023) / 1024;
    hipMemsetAsync(rp, 0, (size_t)n * 4, stream);
    k_hist<<<(nnz + 255) / 256, blk, 0, stream>>>(rows, rp, nnz);
    k_scan_block<<<nb, blk, 0, stream>>>(rp, n, bsum);
    k_scan_top<<<1, blk, 0, stream>>>(bsum, nb);
    k_scan_add_rf<<<(n + 255) / 256, blk, 0, stream>>>(rp, n, bsum, rf);
    k_scatter<<<(nnz + 255) / 256, blk, 0, stream>>>(rows, cols, vals, rf,
            colp, valp, nnz, scale);
}

extern "C" void kernel_launch(void* const* d_in, const int* in_sizes, int n_in,
                              void* d_out, int out_size, void* d_ws, size_t ws_size,
                              hipStream_t stream)
{
    const float* X0  = (const float*)d_in[0];
    const int*  eidx = (const int*)  d_in[1];
    const int*  tidx = (const int*)  d_in[2];
    const int* L0r = (const int*)d_in[3];
    const int* L0c = (const int*)d_in[4];
    const float* L0v = (const float*)d_in[5];
    const int* L1r = (const int*)d_in[6];
    const int* L1c = (const int*)d_in[7];
    const float* L1v = (const float*)d_in[8];
    const int* L2r = (const int*)d_in[9];
    const int* L2c = (const int*)d_in[10];
    const float* L2v = (const float*)d_in[11];
    const int* B1r = (const int*)d_in[12];
    const int* B1c = (const int*)d_in[13];
    const float* B1v = (const float*)d_in[14];
    const int* B2r = (const int*)d_in[15];
    const int* B2c = (const int*)d_in[16];
    const float* B2v = (const float*)d_in[17];
    const float* Wn   = (const float*)d_in[18];
    const float* bn   = (const float*)d_in[19];
    const float* We   = (const float*)d_in[20];
    const float* be   = (const float*)d_in[21];
    const float* Wt   = (const float*)d_in[22];
    const float* bt   = (const float*)d_in[23];
    const float* Wtri = (const float*)d_in[24];
    const float* btri = (const float*)d_in[25];
    const float* pw   = (const float*)d_in[26];

    const int N0 = in_sizes[0] / 128;
    const int N1 = in_sizes[1] / 2;
    const int N2 = in_sizes[2] / 3;
    const int nnz0 = in_sizes[3], nnz1 = in_sizes[6], nnz2 = in_sizes[9];
    const int nnzb1 = in_sizes[12], nnzb2 = in_sizes[15];

    // --- base workspace: S1 | S2 | Ts = 256,000,000 B exactly ---
    char* ws = (char*)d_ws;
    size_t off = 0;
    auto take = [&](size_t bytes) {
        void* p = ws + off;
        off += (bytes + 255) & ~(size_t)255;
        return p;
    };
    float* S1 = (float*)take((size_t)N1 * 512);
    float* S2 = (float*)take((size_t)N2 * 512);
    float* Ts = (float*)take((size_t)N1 * 512);

    auto align256 = [](size_t x) { return (x + 255) & ~(size_t)255; };

    // bit tables overlay Ts head (die before B2-gather writes Ts)
    ulonglong2* Xb = (ulonglong2*)Ts;
    ulonglong2* Eb = (ulonglong2*)((char*)Ts + align256((size_t)N0 * 16));
    ulonglong2* Tb = (ulonglong2*)((char*)Eb + align256((size_t)N1 * 16));

    // d_out overlay: CSR-L1 | CSR-L2 | CSR-B2 | W splits | bsumA  (25.0 MB)
    char* dob = (char*)d_out;
    size_t doff = 0;
    int*   rpL1   = (int*)(dob + doff); doff += align256((size_t)(N1 + 1) * 4);
    int*   rfL1   = (int*)(dob + doff); doff += align256((size_t)(N1 + 1) * 4);
    int*   colpL1 = (int*)(dob + doff); doff += align256((size_t)nnz1 * 4);
    float* valpL1 = (float*)(dob + doff); doff += align256((size_t)nnz1 * 4);
    int*   rpL2   = (int*)(dob + doff); doff += align256((size_t)(N2 + 1) * 4);
    int*   rfL2   = (int*)(dob + doff); doff += align256((size_t)(N2 + 1) * 4);
    int*   colpL2 = (int*)(dob + doff); doff += align256((size_t)nnz2 * 4);
    float* valpL2 = (float*)(dob + doff); doff += align256((size_t)nnz2 * 4);
    int*   rpB2   = (int*)(dob + doff); doff += align256((size_t)(N1 + 1) * 4);
    int*   rfB2   = (int*)(dob + doff); doff += align256((size_t)(N1 + 1) * 4);
    int*   colpB2 = (int*)(dob + doff); doff += align256((size_t)nnzb2 * 4);
    float* valpB2 = (float*)(dob + doff); doff += align256((size_t)nnzb2 * 4);
    short* WThi  = (short*)(dob + doff); doff += 32768;
    short* WTlo  = (short*)(dob + doff); doff += 32768;
    short* WEhi  = (short*)(dob + doff); doff += 32768;
    short* WElo  = (short*)(dob + doff); doff += 32768;
    short* WRhi  = (short*)(dob + doff); doff += 32768;
    short* WRlo  = (short*)(dob + doff); doff += 32768;
    int*   bsumA = (int*)(dob + doff); doff += 1024;

    // S1-region overlay for phase B (after U-GEMM consumes H1)
    char* s1b = (char*)S1;
    size_t soff = 0;
    ulonglong2* Xb2 = (ulonglong2*)(s1b + soff); soff += align256((size_t)N0 * 16);
    int*   rpL0   = (int*)(s1b + soff); soff += align256((size_t)(N0 + 1) * 4);
    int*   rfL0   = (int*)(s1b + soff); soff += align256((size_t)(N0 + 1) * 4);
    int*   colpL0 = (int*)(s1b + soff); soff += align256((size_t)nnz0 * 4);
    float* valpL0 = (float*)(s1b + soff); soff += align256((size_t)nnz0 * 4);
    int*   rpB1   = (int*)(s1b + soff); soff += align256((size_t)(N0 + 1) * 4);
    int*   rfB1   = (int*)(s1b + soff); soff += align256((size_t)(N0 + 1) * 4);
    int*   colpB1 = (int*)(s1b + soff); soff += align256((size_t)nnzb1 * 4);
    float* valpB1 = (float*)(s1b + soff); soff += align256((size_t)nnzb1 * 4);
    short* WNhi  = (short*)(s1b + soff); soff += 32768;
    short* WNlo  = (short*)(s1b + soff); soff += 32768;
    int*   bsumB = (int*)(s1b + soff); soff += 1024;

    dim3 blk(256);

    // --- phase A: bit tables ---
    k_bits_node<<<(N0 + 3) / 4, blk, 0, stream>>>(X0, Xb, N0);
    k_bits_edge<<<(N1 + 255) / 256, blk, 0, stream>>>(eidx, Xb, Eb, N1);
    k_bits_tri<<<(N2 + 255) / 256, blk, 0, stream>>>(tidx, Xb, Tb, N2);

    // --- weight splits + CSR builds in d_out ---
    k_wsplit<<<64, blk, 0, stream>>>(Wt,   WThi, WTlo, 16384);
    k_wsplit<<<64, blk, 0, stream>>>(We,   WEhi, WElo, 16384);
    k_wsplit<<<64, blk, 0, stream>>>(Wtri, WRhi, WRlo, 16384);
    build_csr(L1r, L1c, L1v, rpL1, rfL1, colpL1, valpL1, bsumA, N1, nnz1, 1.0f, stream);
    build_csr(L2r, L2c, L2v, rpL2, rfL2, colpL2, valpL2, bsumA, N2, nnz2, 1.0f, stream);
    build_csr(B2r, B2c, B2v, rpB2, rfB2, colpB2, valpB2, bsumA, N1, nnzb2, 1.0f, stream);

    // --- binary gathers (no atomics, no memsets) ---
    k_gather_bin<<<(N1 + 3) / 4, blk, 0, stream>>>(rpL1, colpL1, valpL1, Eb, S1, N1);
    k_gather_bin<<<(N2 + 3) / 4, blk, 0, stream>>>(rpL2, colpL2, valpL2, Tb, S2, N2);

    // --- H2 = prelu(S2 @ Wt^T + bt); H1 = prelu(S1 @ We^T + be) (in place) ---
    k_gemm_mfma<1, 0><<<(N2 + 63) / 64, blk, 0, stream>>>(S2, WThi, WTlo, bt,
            nullptr, pw, S2, N2, 1.0f);
    k_gemm_mfma<1, 0><<<(N1 + 63) / 64, blk, 0, stream>>>(S1, WEhi, WElo, be,
            nullptr, pw, S1, N1, 1.0f);

    // --- Ts = B2 @ H2 (clobbers bit tables; they are dead) ---
    k_gather_write<<<(N1 + 3) / 4, blk, 0, stream>>>(rpB2, colpB2, valpB2, S2, Ts, N1);

    // --- U = (Ts @ Wtri^T + btri) + H1 (in place; H1/S1 dies here) ---
    k_gemm_mfma<0, 1><<<(N1 + 63) / 64, blk, 0, stream>>>(Ts, WRhi, WRlo, btri,
            S1, pw, Ts, N1, 1.0f);

    // --- phase B in S1 region: node bits + CSR-L0 + CSR-B1 + Wn split ---
    k_bits_node<<<(N0 + 3) / 4, blk, 0, stream>>>(X0, Xb2, N0);
    k_wsplit<<<64, blk, 0, stream>>>(Wn, WNhi, WNlo, 16384);
    build_csr(L0r, L0c, L0v, rpL0, rfL0, colpL0, valpL0, bsumB, N0, nnz0, 1.0f, stream);
    build_csr(B1r, B1c, B1v, rpB1, rfB1, colpB1, valpB1, bsumB, N0, nnzb1, 1.0f / 3.0f, stream);

    // --- S0 = L0 @ X0b  ->  d_out (d_out scratch all dead by now) ---
    k_gather_bin<<<(N0 + 3) / 4, blk, 0, stream>>>(rpL0, colpL0, valpL0, Xb2,
            (float*)d_out, N0);
    // --- d_out = prelu(S0 @ Wn^T + bn) / 3 (in place) ---
    k_gemm_mfma<1, 0><<<(N0 + 63) / 64, blk, 0, stream>>>((float*)d_out, WNhi, WNlo,
            bn, nullptr, pw, (float*)d_out, N0, 1.0f / 3.0f);
    // --- d_out += B1 @ U (valp pre-scaled 1/3; non-atomic) ---
    k_gather_add<<<(N0 + 3) / 4, blk, 0, stream>>>(rpB1, colpB1, valpB1, Ts,
            (float*)d_out, N0);
}

// Round 14
// 1056.289 us; speedup vs baseline: 1.1498x; 1.1498x over previous
//
#include <hip/hip_runtime.h>
#include <hip/hip_bf16.h>
#include <stdint.h>

// ---------------------------------------------------------------------------
// PlanetoidSCN R13: binary-gather FUSED into MFMA GEMM (S0/S1/S2 never hit
// HBM) + CSR-gather for B2/B1 + split-bf16 MFMA GEMMs.
//
// ws = S1 | S2 | Ts = 256,000,000 B exactly (known-safe since R6).
// Overlays (identical liveness to R12, re-audited):
//   Ts head   : Xb/Eb/Tb bit tables   (die after fused N2/N1 GEMMs, before
//                                      B2-gather writes Ts)
//   d_out     : CSR-L1, CSR-L2, CSR-B2, Wt/We/Wtri splits (25.0 MB; all dead
//               before fused-H0 writes d_out)
//   S1 region : Xb2, CSR-L0, CSR-B1, Wn split (after U-GEMM consumes H1)
// ---------------------------------------------------------------------------

typedef __attribute__((ext_vector_type(8))) short bf16x8;
typedef __attribute__((ext_vector_type(4))) float f32x4;

__device__ __forceinline__ short f2bf(float x) {
    __hip_bfloat16 h = __float2bfloat16(x);
    return *reinterpret_cast<short*>(&h);
}
__device__ __forceinline__ float bf2f(short s) {
    __hip_bfloat16 h = *reinterpret_cast<__hip_bfloat16*>(&s);
    return __bfloat162float(h);
}

__global__ __launch_bounds__(256) void k_bits_node(const float* __restrict__ X,
        ulonglong2* __restrict__ bits, int n)
{
    int wid = (blockIdx.x * 256 + threadIdx.x) >> 6;
    int lane = threadIdx.x & 63;
    if (wid >= n) return;
    const float* row = X + (size_t)wid * 128;
    unsigned long long m0 = __ballot(row[lane] != 0.0f);
    unsigned long long m1 = __ballot(row[lane + 64] != 0.0f);
    if (lane == 0) { bits[wid].x = m0; bits[wid].y = m1; }
}

__global__ __launch_bounds__(256) void k_bits_edge(const int* __restrict__ idx,
        const ulonglong2* __restrict__ nb, ulonglong2* __restrict__ outb, int n)
{
    int e = blockIdx.x * 256 + threadIdx.x;
    if (e >= n) return;
    ulonglong2 a = nb[idx[2 * e]];
    ulonglong2 b = nb[idx[2 * e + 1]];
    ulonglong2 r; r.x = a.x & b.x; r.y = a.y & b.y;
    outb[e] = r;
}

__global__ __launch_bounds__(256) void k_bits_tri(const int* __restrict__ idx,
        const ulonglong2* __restrict__ nb, ulonglong2* __restrict__ outb, int n)
{
    int e = blockIdx.x * 256 + threadIdx.x;
    if (e >= n) return;
    ulonglong2 a = nb[idx[3 * e]];
    ulonglong2 b = nb[idx[3 * e + 1]];
    ulonglong2 c = nb[idx[3 * e + 2]];
    ulonglong2 r; r.x = a.x & b.x & c.x; r.y = a.y & b.y & c.y;
    outb[e] = r;
}

// ---------------- CSR build: histogram -> scan -> scatter -------------------

__global__ __launch_bounds__(256) void k_hist(const int* __restrict__ rows,
        int* __restrict__ rp, int nnz)
{
    int nz = blockIdx.x * 256 + threadIdx.x;
    if (nz >= nnz) return;
    atomicAdd(&rp[rows[nz] + 1], 1);
}

__global__ __launch_bounds__(256) void k_scan_block(int* __restrict__ a, int n,
        int* __restrict__ bsum)
{
    __shared__ int sm[256];
    int b = blockIdx.x, t = threadIdx.x;
    int g = b * 1024 + t * 4;
    int x0 = (g + 0 < n) ? a[g + 0] : 0;
    int x1 = (g + 1 < n) ? a[g + 1] : 0;
    int x2 = (g + 2 < n) ? a[g + 2] : 0;
    int x3 = (g + 3 < n) ? a[g + 3] : 0;
    int ts = x0 + x1 + x2 + x3;
    sm[t] = ts; __syncthreads();
    for (int ofs = 1; ofs < 256; ofs <<= 1) {
        int x = (t >= ofs) ? sm[t - ofs] : 0;
        __syncthreads();
        sm[t] += x;
        __syncthreads();
    }
    int excl = sm[t] - ts;
    if (g + 0 < n) a[g + 0] = excl + x0;
    if (g + 1 < n) a[g + 1] = excl + x0 + x1;
    if (g + 2 < n) a[g + 2] = excl + x0 + x1 + x2;
    if (g + 3 < n) a[g + 3] = excl + ts;
    if (t == 255) bsum[b] = sm[255];
}

__global__ __launch_bounds__(256) void k_scan_top(int* __restrict__ bsum, int nb)
{
    __shared__ int sm[256];
    int t = threadIdx.x;
    int v = (t < nb) ? bsum[t] : 0;
    sm[t] = v; __syncthreads();
    for (int ofs = 1; ofs < 256; ofs <<= 1) {
        int x = (t >= ofs) ? sm[t - ofs] : 0;
        __syncthreads();
        sm[t] += x;
        __syncthreads();
    }
    if (t < nb) bsum[t] = sm[t] - v;   // exclusive
}

// adds block offsets AND writes the rf (running-cursor) copy.
__global__ __launch_bounds__(256) void k_scan_add_rf(int* __restrict__ a, int n,
        const int* __restrict__ bsum, int* __restrict__ rf)
{
    int g = blockIdx.x * 256 + threadIdx.x;
    if (g >= n) return;
    int v = a[g] + bsum[g >> 10];
    a[g] = v;
    rf[g] = v;
}

__global__ __launch_bounds__(256) void k_scatter(const int* __restrict__ rows,
        const int* __restrict__ cols, const float* __restrict__ vals,
        int* __restrict__ rf, int* __restrict__ colp, float* __restrict__ valp,
        int nnz, float scale)
{
    int nz = blockIdx.x * 256 + threadIdx.x;
    if (nz >= nnz) return;
    int r = rows[nz];
    int pos = atomicAdd(&rf[r], 1);
    colp[pos] = cols[nz];
    valp[pos] = vals[nz] * scale;
}

// One wave per row: Out[r] = sum valp[i] * X[colp[i]]  (writes all rows).
__global__ __launch_bounds__(256) void k_gather_write(const int* __restrict__ rp,
        const int* __restrict__ colp, const float* __restrict__ valp,
        const float* __restrict__ X, float* __restrict__ Out, int nrows)
{
    int r = (blockIdx.x * 256 + threadIdx.x) >> 6;
    int lane = threadIdx.x & 63;
    if (r >= nrows) return;
    int s = rp[r], e = rp[r + 1];
    float2 acc = make_float2(0.f, 0.f);
    for (int i = s; i < e; ++i) {
        int c = colp[i];
        float v = valp[i];
        float2 x = *(const float2*)(X + (size_t)c * 128 + lane * 2);
        acc.x += v * x.x;
        acc.y += v * x.y;
    }
    *(float2*)(Out + (size_t)r * 128 + lane * 2) = acc;
}

// One wave per row: Out[r] += sum valp[i] * X[colp[i]]  (skip empty rows).
__global__ __launch_bounds__(256) void k_gather_add(const int* __restrict__ rp,
        const int* __restrict__ colp, const float* __restrict__ valp,
        const float* __restrict__ X, float* __restrict__ Out, int nrows)
{
    int r = (blockIdx.x * 256 + threadIdx.x) >> 6;
    int lane = threadIdx.x & 63;
    if (r >= nrows) return;
    int s = rp[r], e = rp[r + 1];
    if (s == e) return;
    float2 acc = make_float2(0.f, 0.f);
    for (int i = s; i < e; ++i) {
        int c = colp[i];
        float v = valp[i];
        float2 x = *(const float2*)(X + (size_t)c * 128 + lane * 2);
        acc.x += v * x.x;
        acc.y += v * x.y;
    }
    float* o = Out + (size_t)r * 128 + lane * 2;
    float2 cur = *(float2*)o;
    cur.x += acc.x; cur.y += acc.y;
    *(float2*)o = cur;
}

// Split f32 W -> bf16 hi + bf16 lo (RNE both stages).
__global__ __launch_bounds__(256) void k_wsplit(const float* __restrict__ W,
        short* __restrict__ hi, short* __restrict__ lo, int n)
{
    int i = blockIdx.x * 256 + threadIdx.x;
    if (i >= n) return;
    float x = W[i];
    short h = f2bf(x);
    hi[i] = h;
    lo[i] = f2bf(x - bf2f(h));
}

// select-accumulate: a += (bit j of w) ? v : 0, branchless 4-VALU
__device__ __forceinline__ float bitsel(uint32_t w, int j, float v) {
    int m = ((int)(w << (31 - j))) >> 31;            // all-ones iff bit set
    return __int_as_float(m & __float_as_int(v));    // v or +0.0f
}

// ---------------------------------------------------------------------------
// FUSED binary-gather + split-bf16 MFMA GEMM:
//   H = prelu(  (CSR @ bits) @ W^T + b ) * scale
// A-fragment gathered in registers: lane (lm,kg) owns row band+lm, features
// ks*32 + kg*8 + j  (= bit kg*8+j of mask word ks). S never materializes.
// W pre-split hi/lo bf16, staged in LDS at stride 136 (2-way alias = free).
// ---------------------------------------------------------------------------
__global__ __launch_bounds__(256) void k_fused_bin_gemm(
        const int* __restrict__ rp, const int* __restrict__ colp,
        const float* __restrict__ valp, const ulonglong2* __restrict__ bits,
        const short* __restrict__ Whi, const short* __restrict__ Wlo,
        const float* __restrict__ bias, const float* __restrict__ pw,
        float* __restrict__ H, int n_rows, float scale)
{
    __shared__ short Wh[128 * 136];
    __shared__ short Wl[128 * 136];
    const int t = threadIdx.x;

    const uint32_t* gh = (const uint32_t*)Whi;
    const uint32_t* gl = (const uint32_t*)Wlo;
    for (int i = t; i < 128 * 64; i += 256) {      // u32 = 2 bf16
        int r = i >> 6, cp = i & 63;
        *(uint32_t*)&Wh[r * 136 + cp * 2] = gh[r * 64 + cp];
        *(uint32_t*)&Wl[r * 136 + cp * 2] = gl[r * 64 + cp];
    }
    __syncthreads();

    const int lane = t & 63;
    const int lm = lane & 15, kg = lane >> 4;
    const int kg8 = kg * 8;
    const int band = blockIdx.x * 64 + (t >> 6) * 16;
    const int row_a = band + lm;

    // --- in-register binary gather of this lane's 32 A-features ---
    float a32[32];
#pragma unroll
    for (int i = 0; i < 32; ++i) a32[i] = 0.f;
    if (row_a < n_rows) {
        int s = rp[row_a], e = rp[row_a + 1];
        const uint4* b4 = (const uint4*)bits;
        for (int i = s; i < e; ++i) {
            int c = colp[i];
            float v = valp[i];
            uint4 m = b4[c];
            uint32_t w0 = m.x >> kg8, w1 = m.y >> kg8;
            uint32_t w2 = m.z >> kg8, w3 = m.w >> kg8;
#pragma unroll
            for (int j = 0; j < 8; ++j) {
                a32[0 * 8 + j] += bitsel(w0, j, v);
                a32[1 * 8 + j] += bitsel(w1, j, v);
                a32[2 * 8 + j] += bitsel(w2, j, v);
                a32[3 * 8 + j] += bitsel(w3, j, v);
            }
        }
    }

    f32x4 acc[8];
#pragma unroll
    for (int ct = 0; ct < 8; ++ct) acc[ct] = (f32x4){0.f, 0.f, 0.f, 0.f};

#pragma unroll
    for (int ks = 0; ks < 4; ++ks) {
        const int k0 = ks * 32 + kg8;
        bf16x8 ahi, alo;
#pragma unroll
        for (int i = 0; i < 8; ++i) {
            float av = a32[ks * 8 + i];
            short h = f2bf(av);
            ahi[i] = h;
            alo[i] = f2bf(av - bf2f(h));
        }
#pragma unroll
        for (int ct = 0; ct < 8; ++ct) {
            const int brow = ct * 16 + lm;
            bf16x8 bhi = *(const bf16x8*)&Wh[brow * 136 + k0];
            bf16x8 blo = *(const bf16x8*)&Wl[brow * 136 + k0];
            acc[ct] = __builtin_amdgcn_mfma_f32_16x16x32_bf16(ahi, bhi, acc[ct], 0, 0, 0);
            acc[ct] = __builtin_amdgcn_mfma_f32_16x16x32_bf16(ahi, blo, acc[ct], 0, 0, 0);
            acc[ct] = __builtin_amdgcn_mfma_f32_16x16x32_bf16(alo, bhi, acc[ct], 0, 0, 0);
        }
    }

    // C/D: col = ct*16 + lm, row = band + kg*4 + j   (bench-verified mapping)
    const int r0 = band + kg * 4;
    const float w = pw[0];
#pragma unroll
    for (int ct = 0; ct < 8; ++ct) {
        const int col = ct * 16 + lm;
        const float b = bias[col];
#pragma unroll
        for (int j = 0; j < 4; ++j) {
            const int row = r0 + j;
            if (row >= n_rows) continue;
            float x = acc[ct][j] + b;
            x = x >= 0.f ? x : w * x;
            H[(size_t)row * 128 + col] = x * scale;
        }
    }
}

// ---------------------------------------------------------------------------
// Split-bf16 MFMA GEMM (dense A from global): H = epi(S @ W^T + b).
// Used only for U = (Ts @ Wtri^T + btri) + H1.
// ---------------------------------------------------------------------------
template<int PRELU, int ADDSRC>
__global__ __launch_bounds__(256) void k_gemm_mfma(const float* __restrict__ S,
        const short* __restrict__ Whi, const short* __restrict__ Wlo,
        const float* __restrict__ bias, const float* __restrict__ addsrc,
        const float* __restrict__ pw, float* __restrict__ H, int n_rows,
        float scale)
{
    __shared__ short Wh[128 * 136];
    __shared__ short Wl[128 * 136];
    const int t = threadIdx.x;

    const uint32_t* gh = (const uint32_t*)Whi;
    const uint32_t* gl = (const uint32_t*)Wlo;
    for (int i = t; i < 128 * 64; i += 256) {
        int r = i >> 6, cp = i & 63;
        *(uint32_t*)&Wh[r * 136 + cp * 2] = gh[r * 64 + cp];
        *(uint32_t*)&Wl[r * 136 + cp * 2] = gl[r * 64 + cp];
    }
    __syncthreads();

    const int wave = t >> 6, lane = t & 63;
    const int lm = lane & 15, kg = lane >> 4;
    const int band = blockIdx.x * 64 + wave * 16;
    const int row_a = band + lm;
    const bool arow_ok = row_a < n_rows;

    f32x4 acc[8];
#pragma unroll
    for (int ct = 0; ct < 8; ++ct) acc[ct] = (f32x4){0.f, 0.f, 0.f, 0.f};

    for (int ks = 0; ks < 4; ++ks) {
        const int k0 = ks * 32 + kg * 8;
        float a[8];
        if (arow_ok) {
            float4 v0 = *(const float4*)(S + (size_t)row_a * 128 + k0);
            float4 v1 = *(const float4*)(S + (size_t)row_a * 128 + k0 + 4);
            a[0]=v0.x; a[1]=v0.y; a[2]=v0.z; a[3]=v0.w;
            a[4]=v1.x; a[5]=v1.y; a[6]=v1.z; a[7]=v1.w;
        } else {
#pragma unroll
            for (int i = 0; i < 8; ++i) a[i] = 0.f;
        }
        bf16x8 ahi, alo;
#pragma unroll
        for (int i = 0; i < 8; ++i) {
            short h = f2bf(a[i]);
            ahi[i] = h;
            alo[i] = f2bf(a[i] - bf2f(h));
        }
#pragma unroll
        for (int ct = 0; ct < 8; ++ct) {
            const int brow = ct * 16 + lm;
            bf16x8 bhi = *(const bf16x8*)&Wh[brow * 136 + k0];
            bf16x8 blo = *(const bf16x8*)&Wl[brow * 136 + k0];
            acc[ct] = __builtin_amdgcn_mfma_f32_16x16x32_bf16(ahi, bhi, acc[ct], 0, 0, 0);
            acc[ct] = __builtin_amdgcn_mfma_f32_16x16x32_bf16(ahi, blo, acc[ct], 0, 0, 0);
            acc[ct] = __builtin_amdgcn_mfma_f32_16x16x32_bf16(alo, bhi, acc[ct], 0, 0, 0);
        }
    }

    const int r0 = band + kg * 4;
    float w = 0.f;
    if (PRELU) w = pw[0];
#pragma unroll
    for (int ct = 0; ct < 8; ++ct) {
        const int col = ct * 16 + lm;
        const float b = bias[col];
#pragma unroll
        for (int j = 0; j < 4; ++j) {
            const int row = r0 + j;
            if (row >= n_rows) continue;
            float x = acc[ct][j] + b;
            if (PRELU) x = x >= 0.f ? x : w * x;
            x *= scale;
            if (ADDSRC) x += addsrc[(size_t)row * 128 + col];
            H[(size_t)row * 128 + col] = x;
        }
    }
}

// helper to run one CSR build (6 enqueues, shared bsum)
static void build_csr(const int* rows, const int* cols, const float* vals,
                      int* rp, int* rf, int* colp, float* valp, int* bsum,
                      int nrows, int nnz, float scale, hipStream_t stream)
{
    dim3 blk(256);
    int n = nrows + 1;
    int nb = (n + 1023) / 1024;
    hipMemsetAsync(rp, 0, (size_t)n * 4, stream);
    k_hist<<<(nnz + 255) / 256, blk, 0, stream>>>(rows, rp, nnz);
    k_scan_block<<<nb, blk, 0, stream>>>(rp, n, bsum);
    k_scan_top<<<1, blk, 0, stream>>>(bsum, nb);
    k_scan_add_rf<<<(n + 255) / 256, blk, 0, stream>>>(rp, n, bsum, rf);
    k_scatter<<<(nnz + 255) / 256, blk, 0, stream>>>(rows, cols, vals, rf,
            colp, valp, nnz, scale);
}

extern "C" void kernel_launch(void* const* d_in, const int* in_sizes, int n_in,
                              void* d_out, int out_size, void* d_ws, size_t ws_size,
                              hipStream_t stream)
{
    const float* X0  = (const float*)d_in[0];
    const int*  eidx = (const int*)  d_in[1];
    const int*  tidx = (const int*)  d_in[2];
    const int* L0r = (const int*)d_in[3];
    const int* L0c = (const int*)d_in[4];
    const float* L0v = (const float*)d_in[5];
    const int* L1r = (const int*)d_in[6];
    const int* L1c = (const int*)d_in[7];
    const float* L1v = (const float*)d_in[8];
    const int* L2r = (const int*)d_in[9];
    const int* L2c = (const int*)d_in[10];
    const float* L2v = (const float*)d_in[11];
    const int* B1r = (const int*)d_in[12];
    const int* B1c = (const int*)d_in[13];
    const float* B1v = (const float*)d_in[14];
    const int* B2r = (const int*)d_in[15];
    const int* B2c = (const int*)d_in[16];
    const float* B2v = (const float*)d_in[17];
    const float* Wn   = (const float*)d_in[18];
    const float* bn   = (const float*)d_in[19];
    const float* We   = (const float*)d_in[20];
    const float* be   = (const float*)d_in[21];
    const float* Wt   = (const float*)d_in[22];
    const float* bt   = (const float*)d_in[23];
    const float* Wtri = (const float*)d_in[24];
    const float* btri = (const float*)d_in[25];
    const float* pw   = (const float*)d_in[26];

    const int N0 = in_sizes[0] / 128;
    const int N1 = in_sizes[1] / 2;
    const int N2 = in_sizes[2] / 3;
    const int nnz0 = in_sizes[3], nnz1 = in_sizes[6], nnz2 = in_sizes[9];
    const int nnzb1 = in_sizes[12], nnzb2 = in_sizes[15];

    // --- base workspace: S1 | S2 | Ts = 256,000,000 B exactly ---
    char* ws = (char*)d_ws;
    size_t off = 0;
    auto take = [&](size_t bytes) {
        void* p = ws + off;
        off += (bytes + 255) & ~(size_t)255;
        return p;
    };
    float* S1 = (float*)take((size_t)N1 * 512);
    float* S2 = (float*)take((size_t)N2 * 512);
    float* Ts = (float*)take((size_t)N1 * 512);

    auto align256 = [](size_t x) { return (x + 255) & ~(size_t)255; };

    // bit tables overlay Ts head (die before B2-gather writes Ts)
    ulonglong2* Xb = (ulonglong2*)Ts;
    ulonglong2* Eb = (ulonglong2*)((char*)Ts + align256((size_t)N0 * 16));
    ulonglong2* Tb = (ulonglong2*)((char*)Eb + align256((size_t)N1 * 16));

    // d_out overlay: CSR-L1 | CSR-L2 | CSR-B2 | W splits | bsumA  (25.0 MB)
    char* dob = (char*)d_out;
    size_t doff = 0;
    int*   rpL1   = (int*)(dob + doff); doff += align256((size_t)(N1 + 1) * 4);
    int*   rfL1   = (int*)(dob + doff); doff += align256((size_t)(N1 + 1) * 4);
    int*   colpL1 = (int*)(dob + doff); doff += align256((size_t)nnz1 * 4);
    float* valpL1 = (float*)(dob + doff); doff += align256((size_t)nnz1 * 4);
    int*   rpL2   = (int*)(dob + doff); doff += align256((size_t)(N2 + 1) * 4);
    int*   rfL2   = (int*)(dob + doff); doff += align256((size_t)(N2 + 1) * 4);
    int*   colpL2 = (int*)(dob + doff); doff += align256((size_t)nnz2 * 4);
    float* valpL2 = (float*)(dob + doff); doff += align256((size_t)nnz2 * 4);
    int*   rpB2   = (int*)(dob + doff); doff += align256((size_t)(N1 + 1) * 4);
    int*   rfB2   = (int*)(dob + doff); doff += align256((size_t)(N1 + 1) * 4);
    int*   colpB2 = (int*)(dob + doff); doff += align256((size_t)nnzb2 * 4);
    float* valpB2 = (float*)(dob + doff); doff += align256((size_t)nnzb2 * 4);
    short* WThi  = (short*)(dob + doff); doff += 32768;
    short* WTlo  = (short*)(dob + doff); doff += 32768;
    short* WEhi  = (short*)(dob + doff); doff += 32768;
    short* WElo  = (short*)(dob + doff); doff += 32768;
    short* WRhi  = (short*)(dob + doff); doff += 32768;
    short* WRlo  = (short*)(dob + doff); doff += 32768;
    int*   bsumA = (int*)(dob + doff); doff += 1024;

    // S1-region overlay for phase B (after U-GEMM consumes H1)
    char* s1b = (char*)S1;
    size_t soff = 0;
    ulonglong2* Xb2 = (ulonglong2*)(s1b + soff); soff += align256((size_t)N0 * 16);
    int*   rpL0   = (int*)(s1b + soff); soff += align256((size_t)(N0 + 1) * 4);
    int*   rfL0   = (int*)(s1b + soff); soff += align256((size_t)(N0 + 1) * 4);
    int*   colpL0 = (int*)(s1b + soff); soff += align256((size_t)nnz0 * 4);
    float* valpL0 = (float*)(s1b + soff); soff += align256((size_t)nnz0 * 4);
    int*   rpB1   = (int*)(s1b + soff); soff += align256((size_t)(N0 + 1) * 4);
    int*   rfB1   = (int*)(s1b + soff); soff += align256((size_t)(N0 + 1) * 4);
    int*   colpB1 = (int*)(s1b + soff); soff += align256((size_t)nnzb1 * 4);
    float* valpB1 = (float*)(s1b + soff); soff += align256((size_t)nnzb1 * 4);
    short* WNhi  = (short*)(s1b + soff); soff += 32768;
    short* WNlo  = (short*)(s1b + soff); soff += 32768;
    int*   bsumB = (int*)(s1b + soff); soff += 1024;

    dim3 blk(256);

    // --- phase A: bit tables ---
    k_bits_node<<<(N0 + 3) / 4, blk, 0, stream>>>(X0, Xb, N0);
    k_bits_edge<<<(N1 + 255) / 256, blk, 0, stream>>>(eidx, Xb, Eb, N1);
    k_bits_tri<<<(N2 + 255) / 256, blk, 0, stream>>>(tidx, Xb, Tb, N2);

    // --- weight splits + CSR builds in d_out ---
    k_wsplit<<<64, blk, 0, stream>>>(Wt,   WThi, WTlo, 16384);
    k_wsplit<<<64, blk, 0, stream>>>(We,   WEhi, WElo, 16384);
    k_wsplit<<<64, blk, 0, stream>>>(Wtri, WRhi, WRlo, 16384);
    build_csr(L1r, L1c, L1v, rpL1, rfL1, colpL1, valpL1, bsumA, N1, nnz1, 1.0f, stream);
    build_csr(L2r, L2c, L2v, rpL2, rfL2, colpL2, valpL2, bsumA, N2, nnz2, 1.0f, stream);
    build_csr(B2r, B2c, B2v, rpB2, rfB2, colpB2, valpB2, bsumA, N1, nnzb2, 1.0f, stream);

    // --- FUSED: H2 = prelu((L2 @ X2f) @ Wt^T + bt)  -> S2 region ---
    k_fused_bin_gemm<<<(N2 + 63) / 64, blk, 0, stream>>>(rpL2, colpL2, valpL2,
            Tb, WThi, WTlo, bt, pw, S2, N2, 1.0f);
    // --- FUSED: H1 = prelu((L1 @ X1f) @ We^T + be)  -> S1 region ---
    k_fused_bin_gemm<<<(N1 + 63) / 64, blk, 0, stream>>>(rpL1, colpL1, valpL1,
            Eb, WEhi, WElo, be, pw, S1, N1, 1.0f);

    // --- Ts = B2 @ H2 (clobbers bit tables; they are dead) ---
    k_gather_write<<<(N1 + 3) / 4, blk, 0, stream>>>(rpB2, colpB2, valpB2, S2, Ts, N1);

    // --- U = (Ts @ Wtri^T + btri) + H1 (in place; H1/S1 dies here) ---
    k_gemm_mfma<0, 1><<<(N1 + 63) / 64, blk, 0, stream>>>(Ts, WRhi, WRlo, btri,
            S1, pw, Ts, N1, 1.0f);

    // --- phase B in S1 region: node bits + CSR-L0 + CSR-B1 + Wn split ---
    k_bits_node<<<(N0 + 3) / 4, blk, 0, stream>>>(X0, Xb2, N0);
    k_wsplit<<<64, blk, 0, stream>>>(Wn, WNhi, WNlo, 16384);
    build_csr(L0r, L0c, L0v, rpL0, rfL0, colpL0, valpL0, bsumB, N0, nnz0, 1.0f, stream);
    build_csr(B1r, B1c, B1v, rpB1, rfB1, colpB1, valpB1, bsumB, N0, nnzb1, 1.0f / 3.0f, stream);

    // --- FUSED: d_out = prelu((L0 @ X0b) @ Wn^T + bn)/3 (d_out scratch dead) ---
    k_fused_bin_gemm<<<(N0 + 63) / 64, blk, 0, stream>>>(rpL0, colpL0, valpL0,
            Xb2, WNhi, WNlo, bn, pw, (float*)d_out, N0, 1.0f / 3.0f);
    // --- d_out += B1 @ U (valp pre-scaled 1/3; non-atomic) ---
    k_gather_add<<<(N0 + 3) / 4, blk, 0, stream>>>(rpB1, colpB1, valpB1, Ts,
            (float*)d_out, N0);
}

// Round 15
// 974.094 us; speedup vs baseline: 1.2468x; 1.0844x over previous
//
#include <hip/hip_runtime.h>
#include <hip/hip_bf16.h>
#include <stdint.h>

// ---------------------------------------------------------------------------
// PlanetoidSCN R15 = R13 + 512-thread GEMM blocks (occupancy fix).
// R14 counters: fused GEMM at 18.7% occupancy (68KB LDS -> 2 blk/CU x 4
// waves). 512-thread blocks keep LDS/block identical -> 16 waves/CU.
//
// ws = S1 | S2 | Ts = 256,000,000 B exactly (known-safe since R6).
// Overlays identical to R13 (audited twice).
// ---------------------------------------------------------------------------

typedef __attribute__((ext_vector_type(8))) short bf16x8;
typedef __attribute__((ext_vector_type(4))) float f32x4;

__device__ __forceinline__ short f2bf(float x) {
    __hip_bfloat16 h = __float2bfloat16(x);
    return *reinterpret_cast<short*>(&h);
}
__device__ __forceinline__ float bf2f(short s) {
    __hip_bfloat16 h = *reinterpret_cast<__hip_bfloat16*>(&s);
    return __bfloat162float(h);
}

__global__ __launch_bounds__(256) void k_bits_node(const float* __restrict__ X,
        ulonglong2* __restrict__ bits, int n)
{
    int wid = (blockIdx.x * 256 + threadIdx.x) >> 6;
    int lane = threadIdx.x & 63;
    if (wid >= n) return;
    const float* row = X + (size_t)wid * 128;
    unsigned long long m0 = __ballot(row[lane] != 0.0f);
    unsigned long long m1 = __ballot(row[lane + 64] != 0.0f);
    if (lane == 0) { bits[wid].x = m0; bits[wid].y = m1; }
}

__global__ __launch_bounds__(256) void k_bits_edge(const int* __restrict__ idx,
        const ulonglong2* __restrict__ nb, ulonglong2* __restrict__ outb, int n)
{
    int e = blockIdx.x * 256 + threadIdx.x;
    if (e >= n) return;
    ulonglong2 a = nb[idx[2 * e]];
    ulonglong2 b = nb[idx[2 * e + 1]];
    ulonglong2 r; r.x = a.x & b.x; r.y = a.y & b.y;
    outb[e] = r;
}

__global__ __launch_bounds__(256) void k_bits_tri(const int* __restrict__ idx,
        const ulonglong2* __restrict__ nb, ulonglong2* __restrict__ outb, int n)
{
    int e = blockIdx.x * 256 + threadIdx.x;
    if (e >= n) return;
    ulonglong2 a = nb[idx[3 * e]];
    ulonglong2 b = nb[idx[3 * e + 1]];
    ulonglong2 c = nb[idx[3 * e + 2]];
    ulonglong2 r; r.x = a.x & b.x & c.x; r.y = a.y & b.y & c.y;
    outb[e] = r;
}

// ---------------- CSR build: histogram -> scan -> scatter -------------------

__global__ __launch_bounds__(256) void k_hist(const int* __restrict__ rows,
        int* __restrict__ rp, int nnz)
{
    int nz = blockIdx.x * 256 + threadIdx.x;
    if (nz >= nnz) return;
    atomicAdd(&rp[rows[nz] + 1], 1);
}

__global__ __launch_bounds__(256) void k_scan_block(int* __restrict__ a, int n,
        int* __restrict__ bsum)
{
    __shared__ int sm[256];
    int b = blockIdx.x, t = threadIdx.x;
    int g = b * 1024 + t * 4;
    int x0 = (g + 0 < n) ? a[g + 0] : 0;
    int x1 = (g + 1 < n) ? a[g + 1] : 0;
    int x2 = (g + 2 < n) ? a[g + 2] : 0;
    int x3 = (g + 3 < n) ? a[g + 3] : 0;
    int ts = x0 + x1 + x2 + x3;
    sm[t] = ts; __syncthreads();
    for (int ofs = 1; ofs < 256; ofs <<= 1) {
        int x = (t >= ofs) ? sm[t - ofs] : 0;
        __syncthreads();
        sm[t] += x;
        __syncthreads();
    }
    int excl = sm[t] - ts;
    if (g + 0 < n) a[g + 0] = excl + x0;
    if (g + 1 < n) a[g + 1] = excl + x0 + x1;
    if (g + 2 < n) a[g + 2] = excl + x0 + x1 + x2;
    if (g + 3 < n) a[g + 3] = excl + ts;
    if (t == 255) bsum[b] = sm[255];
}

__global__ __launch_bounds__(256) void k_scan_top(int* __restrict__ bsum, int nb)
{
    __shared__ int sm[256];
    int t = threadIdx.x;
    int v = (t < nb) ? bsum[t] : 0;
    sm[t] = v; __syncthreads();
    for (int ofs = 1; ofs < 256; ofs <<= 1) {
        int x = (t >= ofs) ? sm[t - ofs] : 0;
        __syncthreads();
        sm[t] += x;
        __syncthreads();
    }
    if (t < nb) bsum[t] = sm[t] - v;   // exclusive
}

// adds block offsets AND writes the rf (running-cursor) copy.
__global__ __launch_bounds__(256) void k_scan_add_rf(int* __restrict__ a, int n,
        const int* __restrict__ bsum, int* __restrict__ rf)
{
    int g = blockIdx.x * 256 + threadIdx.x;
    if (g >= n) return;
    int v = a[g] + bsum[g >> 10];
    a[g] = v;
    rf[g] = v;
}

__global__ __launch_bounds__(256) void k_scatter(const int* __restrict__ rows,
        const int* __restrict__ cols, const float* __restrict__ vals,
        int* __restrict__ rf, int* __restrict__ colp, float* __restrict__ valp,
        int nnz, float scale)
{
    int nz = blockIdx.x * 256 + threadIdx.x;
    if (nz >= nnz) return;
    int r = rows[nz];
    int pos = atomicAdd(&rf[r], 1);
    colp[pos] = cols[nz];
    valp[pos] = vals[nz] * scale;
}

// One wave per row: Out[r] = sum valp[i] * X[colp[i]]  (writes all rows).
__global__ __launch_bounds__(256) void k_gather_write(const int* __restrict__ rp,
        const int* __restrict__ colp, const float* __restrict__ valp,
        const float* __restrict__ X, float* __restrict__ Out, int nrows)
{
    int r = (blockIdx.x * 256 + threadIdx.x) >> 6;
    int lane = threadIdx.x & 63;
    if (r >= nrows) return;
    int s = rp[r], e = rp[r + 1];
    float2 acc = make_float2(0.f, 0.f);
    for (int i = s; i < e; ++i) {
        int c = colp[i];
        float v = valp[i];
        float2 x = *(const float2*)(X + (size_t)c * 128 + lane * 2);
        acc.x += v * x.x;
        acc.y += v * x.y;
    }
    *(float2*)(Out + (size_t)r * 128 + lane * 2) = acc;
}

// One wave per row: Out[r] += sum valp[i] * X[colp[i]]  (skip empty rows).
__global__ __launch_bounds__(256) void k_gather_add(const int* __restrict__ rp,
        const int* __restrict__ colp, const float* __restrict__ valp,
        const float* __restrict__ X, float* __restrict__ Out, int nrows)
{
    int r = (blockIdx.x * 256 + threadIdx.x) >> 6;
    int lane = threadIdx.x & 63;
    if (r >= nrows) return;
    int s = rp[r], e = rp[r + 1];
    if (s == e) return;
    float2 acc = make_float2(0.f, 0.f);
    for (int i = s; i < e; ++i) {
        int c = colp[i];
        float v = valp[i];
        float2 x = *(const float2*)(X + (size_t)c * 128 + lane * 2);
        acc.x += v * x.x;
        acc.y += v * x.y;
    }
    float* o = Out + (size_t)r * 128 + lane * 2;
    float2 cur = *(float2*)o;
    cur.x += acc.x; cur.y += acc.y;
    *(float2*)o = cur;
}

// Split f32 W -> bf16 hi + bf16 lo (RNE both stages).
__global__ __launch_bounds__(256) void k_wsplit(const float* __restrict__ W,
        short* __restrict__ hi, short* __restrict__ lo, int n)
{
    int i = blockIdx.x * 256 + threadIdx.x;
    if (i >= n) return;
    float x = W[i];
    short h = f2bf(x);
    hi[i] = h;
    lo[i] = f2bf(x - bf2f(h));
}

// select-accumulate: a += (bit j of w) ? v : 0, branchless
__device__ __forceinline__ float bitsel(uint32_t w, int j, float v) {
    int m = ((int)(w << (31 - j))) >> 31;            // all-ones iff bit set
    return __int_as_float(m & __float_as_int(v));    // v or +0.0f
}

// ---------------------------------------------------------------------------
// FUSED binary-gather + split-bf16 MFMA GEMM, 512 threads (8 waves,
// 128 rows/block). Same 68KB LDS -> 2 blocks/CU -> 16 waves/CU (was 8).
// ---------------------------------------------------------------------------
__global__ __launch_bounds__(512) void k_fused_bin_gemm(
        const int* __restrict__ rp, const int* __restrict__ colp,
        const float* __restrict__ valp, const ulonglong2* __restrict__ bits,
        const short* __restrict__ Whi, const short* __restrict__ Wlo,
        const float* __restrict__ bias, const float* __restrict__ pw,
        float* __restrict__ H, int n_rows, float scale)
{
    __shared__ short Wh[128 * 136];
    __shared__ short Wl[128 * 136];
    const int t = threadIdx.x;

    const uint32_t* gh = (const uint32_t*)Whi;
    const uint32_t* gl = (const uint32_t*)Wlo;
    for (int i = t; i < 128 * 64; i += 512) {      // u32 = 2 bf16
        int r = i >> 6, cp = i & 63;
        *(uint32_t*)&Wh[r * 136 + cp * 2] = gh[r * 64 + cp];
        *(uint32_t*)&Wl[r * 136 + cp * 2] = gl[r * 64 + cp];
    }
    __syncthreads();

    const int lane = t & 63;
    const int lm = lane & 15, kg = lane >> 4;
    const int kg8 = kg * 8;
    const int band = blockIdx.x * 128 + (t >> 6) * 16;
    const int row_a = band + lm;

    // --- in-register binary gather of this lane's 32 A-features ---
    float a32[32];
#pragma unroll
    for (int i = 0; i < 32; ++i) a32[i] = 0.f;
    if (row_a < n_rows) {
        int s = rp[row_a], e = rp[row_a + 1];
        const uint4* b4 = (const uint4*)bits;
        for (int i = s; i < e; ++i) {
            int c = colp[i];
            float v = valp[i];
            uint4 m = b4[c];
            uint32_t w0 = m.x >> kg8, w1 = m.y >> kg8;
            uint32_t w2 = m.z >> kg8, w3 = m.w >> kg8;
#pragma unroll
            for (int j = 0; j < 8; ++j) {
                a32[0 * 8 + j] += bitsel(w0, j, v);
                a32[1 * 8 + j] += bitsel(w1, j, v);
                a32[2 * 8 + j] += bitsel(w2, j, v);
                a32[3 * 8 + j] += bitsel(w3, j, v);
            }
        }
    }

    f32x4 acc[8];
#pragma unroll
    for (int ct = 0; ct < 8; ++ct) acc[ct] = (f32x4){0.f, 0.f, 0.f, 0.f};

#pragma unroll
    for (int ks = 0; ks < 4; ++ks) {
        const int k0 = ks * 32 + kg8;
        bf16x8 ahi, alo;
#pragma unroll
        for (int i = 0; i < 8; ++i) {
            float av = a32[ks * 8 + i];
            short h = f2bf(av);
            ahi[i] = h;
            alo[i] = f2bf(av - bf2f(h));
        }
#pragma unroll
        for (int ct = 0; ct < 8; ++ct) {
            const int brow = ct * 16 + lm;
            bf16x8 bhi = *(const bf16x8*)&Wh[brow * 136 + k0];
            bf16x8 blo = *(const bf16x8*)&Wl[brow * 136 + k0];
            acc[ct] = __builtin_amdgcn_mfma_f32_16x16x32_bf16(ahi, bhi, acc[ct], 0, 0, 0);
            acc[ct] = __builtin_amdgcn_mfma_f32_16x16x32_bf16(ahi, blo, acc[ct], 0, 0, 0);
            acc[ct] = __builtin_amdgcn_mfma_f32_16x16x32_bf16(alo, bhi, acc[ct], 0, 0, 0);
        }
    }

    // C/D: col = ct*16 + lm, row = band + kg*4 + j   (bench-verified mapping)
    const int r0 = band + kg * 4;
    const float w = pw[0];
#pragma unroll
    for (int ct = 0; ct < 8; ++ct) {
        const int col = ct * 16 + lm;
        const float b = bias[col];
#pragma unroll
        for (int j = 0; j < 4; ++j) {
            const int row = r0 + j;
            if (row >= n_rows) continue;
            float x = acc[ct][j] + b;
            x = x >= 0.f ? x : w * x;
            H[(size_t)row * 128 + col] = x * scale;
        }
    }
}

// ---------------------------------------------------------------------------
// Split-bf16 MFMA GEMM (dense A), 512 threads / 128 rows per block.
// Used only for U = (Ts @ Wtri^T + btri) + H1.
// ---------------------------------------------------------------------------
template<int PRELU, int ADDSRC>
__global__ __launch_bounds__(512) void k_gemm_mfma(const float* __restrict__ S,
        const short* __restrict__ Whi, const short* __restrict__ Wlo,
        const float* __restrict__ bias, const float* __restrict__ addsrc,
        const float* __restrict__ pw, float* __restrict__ H, int n_rows,
        float scale)
{
    __shared__ short Wh[128 * 136];
    __shared__ short Wl[128 * 136];
    const int t = threadIdx.x;

    const uint32_t* gh = (const uint32_t*)Whi;
    const uint32_t* gl = (const uint32_t*)Wlo;
    for (int i = t; i < 128 * 64; i += 512) {
        int r = i >> 6, cp = i & 63;
        *(uint32_t*)&Wh[r * 136 + cp * 2] = gh[r * 64 + cp];
        *(uint32_t*)&Wl[r * 136 + cp * 2] = gl[r * 64 + cp];
    }
    __syncthreads();

    const int lane = t & 63;
    const int lm = lane & 15, kg = lane >> 4;
    const int band = blockIdx.x * 128 + (t >> 6) * 16;
    const int row_a = band + lm;
    const bool arow_ok = row_a < n_rows;

    f32x4 acc[8];
#pragma unroll
    for (int ct = 0; ct < 8; ++ct) acc[ct] = (f32x4){0.f, 0.f, 0.f, 0.f};

    for (int ks = 0; ks < 4; ++ks) {
        const int k0 = ks * 32 + kg * 8;
        float a[8];
        if (arow_ok) {
            float4 v0 = *(const float4*)(S + (size_t)row_a * 128 + k0);
            float4 v1 = *(const float4*)(S + (size_t)row_a * 128 + k0 + 4);
            a[0]=v0.x; a[1]=v0.y; a[2]=v0.z; a[3]=v0.w;
            a[4]=v1.x; a[5]=v1.y; a[6]=v1.z; a[7]=v1.w;
        } else {
#pragma unroll
            for (int i = 0; i < 8; ++i) a[i] = 0.f;
        }
        bf16x8 ahi, alo;
#pragma unroll
        for (int i = 0; i < 8; ++i) {
            short h = f2bf(a[i]);
            ahi[i] = h;
            alo[i] = f2bf(a[i] - bf2f(h));
        }
#pragma unroll
        for (int ct = 0; ct < 8; ++ct) {
            const int brow = ct * 16 + lm;
            bf16x8 bhi = *(const bf16x8*)&Wh[brow * 136 + k0];
            bf16x8 blo = *(const bf16x8*)&Wl[brow * 136 + k0];
            acc[ct] = __builtin_amdgcn_mfma_f32_16x16x32_bf16(ahi, bhi, acc[ct], 0, 0, 0);
            acc[ct] = __builtin_amdgcn_mfma_f32_16x16x32_bf16(ahi, blo, acc[ct], 0, 0, 0);
            acc[ct] = __builtin_amdgcn_mfma_f32_16x16x32_bf16(alo, bhi, acc[ct], 0, 0, 0);
        }
    }

    const int r0 = band + kg * 4;
    float w = 0.f;
    if (PRELU) w = pw[0];
#pragma unroll
    for (int ct = 0; ct < 8; ++ct) {
        const int col = ct * 16 + lm;
        const float b = bias[col];
#pragma unroll
        for (int j = 0; j < 4; ++j) {
            const int row = r0 + j;
            if (row >= n_rows) continue;
            float x = acc[ct][j] + b;
            if (PRELU) x = x >= 0.f ? x : w * x;
            x *= scale;
            if (ADDSRC) x += addsrc[(size_t)row * 128 + col];
            H[(size_t)row * 128 + col] = x;
        }
    }
}

// helper to run one CSR build (6 enqueues, shared bsum)
static void build_csr(const int* rows, const int* cols, const float* vals,
                      int* rp, int* rf, int* colp, float* valp, int* bsum,
                      int nrows, int nnz, float scale, hipStream_t stream)
{
    dim3 blk(256);
    int n = nrows + 1;
    int nb = (n + 1023) / 1024;
    hipMemsetAsync(rp, 0, (size_t)n * 4, stream);
    k_hist<<<(nnz + 255) / 256, blk, 0, stream>>>(rows, rp, nnz);
    k_scan_block<<<nb, blk, 0, stream>>>(rp, n, bsum);
    k_scan_top<<<1, blk, 0, stream>>>(bsum, nb);
    k_scan_add_rf<<<(n + 255) / 256, blk, 0, stream>>>(rp, n, bsum, rf);
    k_scatter<<<(nnz + 255) / 256, blk, 0, stream>>>(rows, cols, vals, rf,
            colp, valp, nnz, scale);
}

extern "C" void kernel_launch(void* const* d_in, const int* in_sizes, int n_in,
                              void* d_out, int out_size, void* d_ws, size_t ws_size,
                              hipStream_t stream)
{
    const float* X0  = (const float*)d_in[0];
    const int*  eidx = (const int*)  d_in[1];
    const int*  tidx = (const int*)  d_in[2];
    const int* L0r = (const int*)d_in[3];
    const int* L0c = (const int*)d_in[4];
    const float* L0v = (const float*)d_in[5];
    const int* L1r = (const int*)d_in[6];
    const int* L1c = (const int*)d_in[7];
    const float* L1v = (const float*)d_in[8];
    const int* L2r = (const int*)d_in[9];
    const int* L2c = (const int*)d_in[10];
    const float* L2v = (const float*)d_in[11];
    const int* B1r = (const int*)d_in[12];
    const int* B1c = (const int*)d_in[13];
    const float* B1v = (const float*)d_in[14];
    const int* B2r = (const int*)d_in[15];
    const int* B2c = (const int*)d_in[16];
    const float* B2v = (const float*)d_in[17];
    const float* Wn   = (const float*)d_in[18];
    const float* bn   = (const float*)d_in[19];
    const float* We   = (const float*)d_in[20];
    const float* be   = (const float*)d_in[21];
    const float* Wt   = (const float*)d_in[22];
    const float* bt   = (const float*)d_in[23];
    const float* Wtri = (const float*)d_in[24];
    const float* btri = (const float*)d_in[25];
    const float* pw   = (const float*)d_in[26];

    const int N0 = in_sizes[0] / 128;
    const int N1 = in_sizes[1] / 2;
    const int N2 = in_sizes[2] / 3;
    const int nnz0 = in_sizes[3], nnz1 = in_sizes[6], nnz2 = in_sizes[9];
    const int nnzb1 = in_sizes[12], nnzb2 = in_sizes[15];

    // --- base workspace: S1 | S2 | Ts = 256,000,000 B exactly ---
    char* ws = (char*)d_ws;
    size_t off = 0;
    auto take = [&](size_t bytes) {
        void* p = ws + off;
        off += (bytes + 255) & ~(size_t)255;
        return p;
    };
    float* S1 = (float*)take((size_t)N1 * 512);
    float* S2 = (float*)take((size_t)N2 * 512);
    float* Ts = (float*)take((size_t)N1 * 512);

    auto align256 = [](size_t x) { return (x + 255) & ~(size_t)255; };

    // bit tables overlay Ts head (die before B2-gather writes Ts)
    ulonglong2* Xb = (ulonglong2*)Ts;
    ulonglong2* Eb = (ulonglong2*)((char*)Ts + align256((size_t)N0 * 16));
    ulonglong2* Tb = (ulonglong2*)((char*)Eb + align256((size_t)N1 * 16));

    // d_out overlay: CSR-L1 | CSR-L2 | CSR-B2 | W splits | bsumA  (25.0 MB)
    char* dob = (char*)d_out;
    size_t doff = 0;
    int*   rpL1   = (int*)(dob + doff); doff += align256((size_t)(N1 + 1) * 4);
    int*   rfL1   = (int*)(dob + doff); doff += align256((size_t)(N1 + 1) * 4);
    int*   colpL1 = (int*)(dob + doff); doff += align256((size_t)nnz1 * 4);
    float* valpL1 = (float*)(dob + doff); doff += align256((size_t)nnz1 * 4);
    int*   rpL2   = (int*)(dob + doff); doff += align256((size_t)(N2 + 1) * 4);
    int*   rfL2   = (int*)(dob + doff); doff += align256((size_t)(N2 + 1) * 4);
    int*   colpL2 = (int*)(dob + doff); doff += align256((size_t)nnz2 * 4);
    float* valpL2 = (float*)(dob + doff); doff += align256((size_t)nnz2 * 4);
    int*   rpB2   = (int*)(dob + doff); doff += align256((size_t)(N1 + 1) * 4);
    int*   rfB2   = (int*)(dob + doff); doff += align256((size_t)(N1 + 1) * 4);
    int*   colpB2 = (int*)(dob + doff); doff += align256((size_t)nnzb2 * 4);
    float* valpB2 = (float*)(dob + doff); doff += align256((size_t)nnzb2 * 4);
    short* WThi  = (short*)(dob + doff); doff += 32768;
    short* WTlo  = (short*)(dob + doff); doff += 32768;
    short* WEhi  = (short*)(dob + doff); doff += 32768;
    short* WElo  = (short*)(dob + doff); doff += 32768;
    short* WRhi  = (short*)(dob + doff); doff += 32768;
    short* WRlo  = (short*)(dob + doff); doff += 32768;
    int*   bsumA = (int*)(dob + doff); doff += 1024;

    // S1-region overlay for phase B (after U-GEMM consumes H1)
    char* s1b = (char*)S1;
    size_t soff = 0;
    ulonglong2* Xb2 = (ulonglong2*)(s1b + soff); soff += align256((size_t)N0 * 16);
    int*   rpL0   = (int*)(s1b + soff); soff += align256((size_t)(N0 + 1) * 4);
    int*   rfL0   = (int*)(s1b + soff); soff += align256((size_t)(N0 + 1) * 4);
    int*   colpL0 = (int*)(s1b + soff); soff += align256((size_t)nnz0 * 4);
    float* valpL0 = (float*)(s1b + soff); soff += align256((size_t)nnz0 * 4);
    int*   rpB1   = (int*)(s1b + soff); soff += align256((size_t)(N0 + 1) * 4);
    int*   rfB1   = (int*)(s1b + soff); soff += align256((size_t)(N0 + 1) * 4);
    int*   colpB1 = (int*)(s1b + soff); soff += align256((size_t)nnzb1 * 4);
    float* valpB1 = (float*)(s1b + soff); soff += align256((size_t)nnzb1 * 4);
    short* WNhi  = (short*)(s1b + soff); soff += 32768;
    short* WNlo  = (short*)(s1b + soff); soff += 32768;
    int*   bsumB = (int*)(s1b + soff); soff += 1024;

    dim3 blk(256);
    dim3 blk512(512);

    // --- phase A: bit tables ---
    k_bits_node<<<(N0 + 3) / 4, blk, 0, stream>>>(X0, Xb, N0);
    k_bits_edge<<<(N1 + 255) / 256, blk, 0, stream>>>(eidx, Xb, Eb, N1);
    k_bits_tri<<<(N2 + 255) / 256, blk, 0, stream>>>(tidx, Xb, Tb, N2);

    // --- weight splits + CSR builds in d_out ---
    k_wsplit<<<64, blk, 0, stream>>>(Wt,   WThi, WTlo, 16384);
    k_wsplit<<<64, blk, 0, stream>>>(We,   WEhi, WElo, 16384);
    k_wsplit<<<64, blk, 0, stream>>>(Wtri, WRhi, WRlo, 16384);
    build_csr(L1r, L1c, L1v, rpL1, rfL1, colpL1, valpL1, bsumA, N1, nnz1, 1.0f, stream);
    build_csr(L2r, L2c, L2v, rpL2, rfL2, colpL2, valpL2, bsumA, N2, nnz2, 1.0f, stream);
    build_csr(B2r, B2c, B2v, rpB2, rfB2, colpB2, valpB2, bsumA, N1, nnzb2, 1.0f, stream);

    // --- FUSED: H2 = prelu((L2 @ X2f) @ Wt^T + bt)  -> S2 region ---
    k_fused_bin_gemm<<<(N2 + 127) / 128, blk512, 0, stream>>>(rpL2, colpL2, valpL2,
            Tb, WThi, WTlo, bt, pw, S2, N2, 1.0f);
    // --- FUSED: H1 = prelu((L1 @ X1f) @ We^T + be)  -> S1 region ---
    k_fused_bin_gemm<<<(N1 + 127) / 128, blk512, 0, stream>>>(rpL1, colpL1, valpL1,
            Eb, WEhi, WElo, be, pw, S1, N1, 1.0f);

    // --- Ts = B2 @ H2 (clobbers bit tables; they are dead) ---
    k_gather_write<<<(N1 + 3) / 4, blk, 0, stream>>>(rpB2, colpB2, valpB2, S2, Ts, N1);

    // --- U = (Ts @ Wtri^T + btri) + H1 (in place; H1/S1 dies here) ---
    k_gemm_mfma<0, 1><<<(N1 + 127) / 128, blk512, 0, stream>>>(Ts, WRhi, WRlo, btri,
            S1, pw, Ts, N1, 1.0f);

    // --- phase B in S1 region: node bits + CSR-L0 + CSR-B1 + Wn split ---
    k_bits_node<<<(N0 + 3) / 4, blk, 0, stream>>>(X0, Xb2, N0);
    k_wsplit<<<64, blk, 0, stream>>>(Wn, WNhi, WNlo, 16384);
    build_csr(L0r, L0c, L0v, rpL0, rfL0, colpL0, valpL0, bsumB, N0, nnz0, 1.0f, stream);
    build_csr(B1r, B1c, B1v, rpB1, rfB1, colpB1, valpB1, bsumB, N0, nnzb1, 1.0f / 3.0f, stream);

    // --- FUSED: d_out = prelu((L0 @ X0b) @ Wn^T + bn)/3 (d_out scratch dead) ---
    k_fused_bin_gemm<<<(N0 + 127) / 128, blk512, 0, stream>>>(rpL0, colpL0, valpL0,
            Xb2, WNhi, WNlo, bn, pw, (float*)d_out, N0, 1.0f / 3.0f);
    // --- d_out += B1 @ U (valp pre-scaled 1/3; non-atomic) ---
    k_gather_add<<<(N0 + 3) / 4, blk, 0, stream>>>(rpB1, colpB1, valpB1, Ts,
            (float*)d_out, N0);
}

// Round 16
// 933.383 us; speedup vs baseline: 1.3012x; 1.0436x over previous
//
#include <hip/hip_runtime.h>
#include <hip/hip_bf16.h>
#include <stdint.h>

// ---------------------------------------------------------------------------
// PlanetoidSCN R16 = R15 + B2-gather fused into the U-GEMM (Ts never does an
// HBM round trip as a GEMM input; k_gather_write + dense k_gemm_mfma -> one
// k_fused_csr_gemm).
//
// ws = S1 | S2 | Ts = 256,000,000 B exactly (known-safe since R6).
// Overlays identical to R13/R15 (audited): Ts-head bit tables die when the
// fused CSR-GEMM writes Ts; d_out CSR/W-split scratch dies before fused-H0;
// S1-region phase-B overlay starts after the fused CSR-GEMM consumes H1.
// ---------------------------------------------------------------------------

typedef __attribute__((ext_vector_type(8))) short bf16x8;
typedef __attribute__((ext_vector_type(4))) float f32x4;

__device__ __forceinline__ short f2bf(float x) {
    __hip_bfloat16 h = __float2bfloat16(x);
    return *reinterpret_cast<short*>(&h);
}
__device__ __forceinline__ float bf2f(short s) {
    __hip_bfloat16 h = *reinterpret_cast<__hip_bfloat16*>(&s);
    return __bfloat162float(h);
}

__global__ __launch_bounds__(256) void k_bits_node(const float* __restrict__ X,
        ulonglong2* __restrict__ bits, int n)
{
    int wid = (blockIdx.x * 256 + threadIdx.x) >> 6;
    int lane = threadIdx.x & 63;
    if (wid >= n) return;
    const float* row = X + (size_t)wid * 128;
    unsigned long long m0 = __ballot(row[lane] != 0.0f);
    unsigned long long m1 = __ballot(row[lane + 64] != 0.0f);
    if (lane == 0) { bits[wid].x = m0; bits[wid].y = m1; }
}

__global__ __launch_bounds__(256) void k_bits_edge(const int* __restrict__ idx,
        const ulonglong2* __restrict__ nb, ulonglong2* __restrict__ outb, int n)
{
    int e = blockIdx.x * 256 + threadIdx.x;
    if (e >= n) return;
    ulonglong2 a = nb[idx[2 * e]];
    ulonglong2 b = nb[idx[2 * e + 1]];
    ulonglong2 r; r.x = a.x & b.x; r.y = a.y & b.y;
    outb[e] = r;
}

__global__ __launch_bounds__(256) void k_bits_tri(const int* __restrict__ idx,
        const ulonglong2* __restrict__ nb, ulonglong2* __restrict__ outb, int n)
{
    int e = blockIdx.x * 256 + threadIdx.x;
    if (e >= n) return;
    ulonglong2 a = nb[idx[3 * e]];
    ulonglong2 b = nb[idx[3 * e + 1]];
    ulonglong2 c = nb[idx[3 * e + 2]];
    ulonglong2 r; r.x = a.x & b.x & c.x; r.y = a.y & b.y & c.y;
    outb[e] = r;
}

// ---------------- CSR build: histogram -> scan -> scatter -------------------

__global__ __launch_bounds__(256) void k_hist(const int* __restrict__ rows,
        int* __restrict__ rp, int nnz)
{
    int nz = blockIdx.x * 256 + threadIdx.x;
    if (nz >= nnz) return;
    atomicAdd(&rp[rows[nz] + 1], 1);
}

__global__ __launch_bounds__(256) void k_scan_block(int* __restrict__ a, int n,
        int* __restrict__ bsum)
{
    __shared__ int sm[256];
    int b = blockIdx.x, t = threadIdx.x;
    int g = b * 1024 + t * 4;
    int x0 = (g + 0 < n) ? a[g + 0] : 0;
    int x1 = (g + 1 < n) ? a[g + 1] : 0;
    int x2 = (g + 2 < n) ? a[g + 2] : 0;
    int x3 = (g + 3 < n) ? a[g + 3] : 0;
    int ts = x0 + x1 + x2 + x3;
    sm[t] = ts; __syncthreads();
    for (int ofs = 1; ofs < 256; ofs <<= 1) {
        int x = (t >= ofs) ? sm[t - ofs] : 0;
        __syncthreads();
        sm[t] += x;
        __syncthreads();
    }
    int excl = sm[t] - ts;
    if (g + 0 < n) a[g + 0] = excl + x0;
    if (g + 1 < n) a[g + 1] = excl + x0 + x1;
    if (g + 2 < n) a[g + 2] = excl + x0 + x1 + x2;
    if (g + 3 < n) a[g + 3] = excl + ts;
    if (t == 255) bsum[b] = sm[255];
}

__global__ __launch_bounds__(256) void k_scan_top(int* __restrict__ bsum, int nb)
{
    __shared__ int sm[256];
    int t = threadIdx.x;
    int v = (t < nb) ? bsum[t] : 0;
    sm[t] = v; __syncthreads();
    for (int ofs = 1; ofs < 256; ofs <<= 1) {
        int x = (t >= ofs) ? sm[t - ofs] : 0;
        __syncthreads();
        sm[t] += x;
        __syncthreads();
    }
    if (t < nb) bsum[t] = sm[t] - v;   // exclusive
}

// adds block offsets AND writes the rf (running-cursor) copy.
__global__ __launch_bounds__(256) void k_scan_add_rf(int* __restrict__ a, int n,
        const int* __restrict__ bsum, int* __restrict__ rf)
{
    int g = blockIdx.x * 256 + threadIdx.x;
    if (g >= n) return;
    int v = a[g] + bsum[g >> 10];
    a[g] = v;
    rf[g] = v;
}

__global__ __launch_bounds__(256) void k_scatter(const int* __restrict__ rows,
        const int* __restrict__ cols, const float* __restrict__ vals,
        int* __restrict__ rf, int* __restrict__ colp, float* __restrict__ valp,
        int nnz, float scale)
{
    int nz = blockIdx.x * 256 + threadIdx.x;
    if (nz >= nnz) return;
    int r = rows[nz];
    int pos = atomicAdd(&rf[r], 1);
    colp[pos] = cols[nz];
    valp[pos] = vals[nz] * scale;
}

// One wave per row: Out[r] += sum valp[i] * X[colp[i]]  (skip empty rows).
__global__ __launch_bounds__(256) void k_gather_add(const int* __restrict__ rp,
        const int* __restrict__ colp, const float* __restrict__ valp,
        const float* __restrict__ X, float* __restrict__ Out, int nrows)
{
    int r = (blockIdx.x * 256 + threadIdx.x) >> 6;
    int lane = threadIdx.x & 63;
    if (r >= nrows) return;
    int s = rp[r], e = rp[r + 1];
    if (s == e) return;
    float2 acc = make_float2(0.f, 0.f);
    for (int i = s; i < e; ++i) {
        int c = colp[i];
        float v = valp[i];
        float2 x = *(const float2*)(X + (size_t)c * 128 + lane * 2);
        acc.x += v * x.x;
        acc.y += v * x.y;
    }
    float* o = Out + (size_t)r * 128 + lane * 2;
    float2 cur = *(float2*)o;
    cur.x += acc.x; cur.y += acc.y;
    *(float2*)o = cur;
}

// Split f32 W -> bf16 hi + bf16 lo (RNE both stages).
__global__ __launch_bounds__(256) void k_wsplit(const float* __restrict__ W,
        short* __restrict__ hi, short* __restrict__ lo, int n)
{
    int i = blockIdx.x * 256 + threadIdx.x;
    if (i >= n) return;
    float x = W[i];
    short h = f2bf(x);
    hi[i] = h;
    lo[i] = f2bf(x - bf2f(h));
}

// select-accumulate: a += (bit j of w) ? v : 0, branchless
__device__ __forceinline__ float bitsel(uint32_t w, int j, float v) {
    int m = ((int)(w << (31 - j))) >> 31;            // all-ones iff bit set
    return __int_as_float(m & __float_as_int(v));    // v or +0.0f
}

// ---------------------------------------------------------------------------
// FUSED binary-gather + split-bf16 MFMA GEMM, 512 threads (8 waves,
// 128 rows/block), 68KB LDS -> 2 blocks/CU -> 16 waves/CU.
// ---------------------------------------------------------------------------
__global__ __launch_bounds__(512) void k_fused_bin_gemm(
        const int* __restrict__ rp, const int* __restrict__ colp,
        const float* __restrict__ valp, const ulonglong2* __restrict__ bits,
        const short* __restrict__ Whi, const short* __restrict__ Wlo,
        const float* __restrict__ bias, const float* __restrict__ pw,
        float* __restrict__ H, int n_rows, float scale)
{
    __shared__ short Wh[128 * 136];
    __shared__ short Wl[128 * 136];
    const int t = threadIdx.x;

    const uint32_t* gh = (const uint32_t*)Whi;
    const uint32_t* gl = (const uint32_t*)Wlo;
    for (int i = t; i < 128 * 64; i += 512) {      // u32 = 2 bf16
        int r = i >> 6, cp = i & 63;
        *(uint32_t*)&Wh[r * 136 + cp * 2] = gh[r * 64 + cp];
        *(uint32_t*)&Wl[r * 136 + cp * 2] = gl[r * 64 + cp];
    }
    __syncthreads();

    const int lane = t & 63;
    const int lm = lane & 15, kg = lane >> 4;
    const int kg8 = kg * 8;
    const int band = blockIdx.x * 128 + (t >> 6) * 16;
    const int row_a = band + lm;

    // --- in-register binary gather of this lane's 32 A-features ---
    float a32[32];
#pragma unroll
    for (int i = 0; i < 32; ++i) a32[i] = 0.f;
    if (row_a < n_rows) {
        int s = rp[row_a], e = rp[row_a + 1];
        const uint4* b4 = (const uint4*)bits;
        for (int i = s; i < e; ++i) {
            int c = colp[i];
            float v = valp[i];
            uint4 m = b4[c];
            uint32_t w0 = m.x >> kg8, w1 = m.y >> kg8;
            uint32_t w2 = m.z >> kg8, w3 = m.w >> kg8;
#pragma unroll
            for (int j = 0; j < 8; ++j) {
                a32[0 * 8 + j] += bitsel(w0, j, v);
                a32[1 * 8 + j] += bitsel(w1, j, v);
                a32[2 * 8 + j] += bitsel(w2, j, v);
                a32[3 * 8 + j] += bitsel(w3, j, v);
            }
        }
    }

    f32x4 acc[8];
#pragma unroll
    for (int ct = 0; ct < 8; ++ct) acc[ct] = (f32x4){0.f, 0.f, 0.f, 0.f};

#pragma unroll
    for (int ks = 0; ks < 4; ++ks) {
        const int k0 = ks * 32 + kg8;
        bf16x8 ahi, alo;
#pragma unroll
        for (int i = 0; i < 8; ++i) {
            float av = a32[ks * 8 + i];
            short h = f2bf(av);
            ahi[i] = h;
            alo[i] = f2bf(av - bf2f(h));
        }
#pragma unroll
        for (int ct = 0; ct < 8; ++ct) {
            const int brow = ct * 16 + lm;
            bf16x8 bhi = *(const bf16x8*)&Wh[brow * 136 + k0];
            bf16x8 blo = *(const bf16x8*)&Wl[brow * 136 + k0];
            acc[ct] = __builtin_amdgcn_mfma_f32_16x16x32_bf16(ahi, bhi, acc[ct], 0, 0, 0);
            acc[ct] = __builtin_amdgcn_mfma_f32_16x16x32_bf16(ahi, blo, acc[ct], 0, 0, 0);
            acc[ct] = __builtin_amdgcn_mfma_f32_16x16x32_bf16(alo, bhi, acc[ct], 0, 0, 0);
        }
    }

    // C/D: col = ct*16 + lm, row = band + kg*4 + j   (bench-verified mapping)
    const int r0 = band + kg * 4;
    const float w = pw[0];
#pragma unroll
    for (int ct = 0; ct < 8; ++ct) {
        const int col = ct * 16 + lm;
        const float b = bias[col];
#pragma unroll
        for (int j = 0; j < 4; ++j) {
            const int row = r0 + j;
            if (row >= n_rows) continue;
            float x = acc[ct][j] + b;
            x = x >= 0.f ? x : w * x;
            H[(size_t)row * 128 + col] = x * scale;
        }
    }
}

// ---------------------------------------------------------------------------
// FUSED dense-CSR-gather + split-bf16 MFMA GEMM (R16 NEW):
//   H = (CSR @ X) @ W^T + bias + addsrc      (no prelu, no scale)
// A-row r = sum_i valp[i] * X[colp[i]]; each lane gathers only its own 32
// features (8 float4 loads per nnz; 4 kg-lanes cover 128B contiguous of the
// X row). Replaces k_gather_write(B2) + dense U-GEMM: Ts write+read (153MB
// HBM) and one dispatch disappear.
// ---------------------------------------------------------------------------
__global__ __launch_bounds__(512) void k_fused_csr_gemm(
        const int* __restrict__ rp, const int* __restrict__ colp,
        const float* __restrict__ valp, const float* __restrict__ X,
        const short* __restrict__ Whi, const short* __restrict__ Wlo,
        const float* __restrict__ bias, const float* __restrict__ addsrc,
        float* __restrict__ H, int n_rows)
{
    __shared__ short Wh[128 * 136];
    __shared__ short Wl[128 * 136];
    const int t = threadIdx.x;

    const uint32_t* gh = (const uint32_t*)Whi;
    const uint32_t* gl = (const uint32_t*)Wlo;
    for (int i = t; i < 128 * 64; i += 512) {
        int r = i >> 6, cp = i & 63;
        *(uint32_t*)&Wh[r * 136 + cp * 2] = gh[r * 64 + cp];
        *(uint32_t*)&Wl[r * 136 + cp * 2] = gl[r * 64 + cp];
    }
    __syncthreads();

    const int lane = t & 63;
    const int lm = lane & 15, kg = lane >> 4;
    const int kg8 = kg * 8;
    const int band = blockIdx.x * 128 + (t >> 6) * 16;
    const int row_a = band + lm;

    // --- in-register dense gather of this lane's 32 A-features ---
    float a32[32];
#pragma unroll
    for (int i = 0; i < 32; ++i) a32[i] = 0.f;
    if (row_a < n_rows) {
        int s = rp[row_a], e = rp[row_a + 1];
        for (int i = s; i < e; ++i) {
            const float* xr = X + (size_t)colp[i] * 128 + kg8;
            float v = valp[i];
#pragma unroll
            for (int ks = 0; ks < 4; ++ks) {
                float4 p0 = *(const float4*)(xr + ks * 32);
                float4 p1 = *(const float4*)(xr + ks * 32 + 4);
                a32[ks * 8 + 0] += v * p0.x;
                a32[ks * 8 + 1] += v * p0.y;
                a32[ks * 8 + 2] += v * p0.z;
                a32[ks * 8 + 3] += v * p0.w;
                a32[ks * 8 + 4] += v * p1.x;
                a32[ks * 8 + 5] += v * p1.y;
                a32[ks * 8 + 6] += v * p1.z;
                a32[ks * 8 + 7] += v * p1.w;
            }
        }
    }

    f32x4 acc[8];
#pragma unroll
    for (int ct = 0; ct < 8; ++ct) acc[ct] = (f32x4){0.f, 0.f, 0.f, 0.f};

#pragma unroll
    for (int ks = 0; ks < 4; ++ks) {
        const int k0 = ks * 32 + kg8;
        bf16x8 ahi, alo;
#pragma unroll
        for (int i = 0; i < 8; ++i) {
            float av = a32[ks * 8 + i];
            short h = f2bf(av);
            ahi[i] = h;
            alo[i] = f2bf(av - bf2f(h));
        }
#pragma unroll
        for (int ct = 0; ct < 8; ++ct) {
            const int brow = ct * 16 + lm;
            bf16x8 bhi = *(const bf16x8*)&Wh[brow * 136 + k0];
            bf16x8 blo = *(const bf16x8*)&Wl[brow * 136 + k0];
            acc[ct] = __builtin_amdgcn_mfma_f32_16x16x32_bf16(ahi, bhi, acc[ct], 0, 0, 0);
            acc[ct] = __builtin_amdgcn_mfma_f32_16x16x32_bf16(ahi, blo, acc[ct], 0, 0, 0);
            acc[ct] = __builtin_amdgcn_mfma_f32_16x16x32_bf16(alo, bhi, acc[ct], 0, 0, 0);
        }
    }

    const int r0 = band + kg * 4;
#pragma unroll
    for (int ct = 0; ct < 8; ++ct) {
        const int col = ct * 16 + lm;
        const float b = bias[col];
#pragma unroll
        for (int j = 0; j < 4; ++j) {
            const int row = r0 + j;
            if (row >= n_rows) continue;
            float x = acc[ct][j] + b + addsrc[(size_t)row * 128 + col];
            H[(size_t)row * 128 + col] = x;
        }
    }
}

// helper to run one CSR build (6 enqueues, shared bsum)
static void build_csr(const int* rows, const int* cols, const float* vals,
                      int* rp, int* rf, int* colp, float* valp, int* bsum,
                      int nrows, int nnz, float scale, hipStream_t stream)
{
    dim3 blk(256);
    int n = nrows + 1;
    int nb = (n + 1023) / 1024;
    hipMemsetAsync(rp, 0, (size_t)n * 4, stream);
    k_hist<<<(nnz + 255) / 256, blk, 0, stream>>>(rows, rp, nnz);
    k_scan_block<<<nb, blk, 0, stream>>>(rp, n, bsum);
    k_scan_top<<<1, blk, 0, stream>>>(bsum, nb);
    k_scan_add_rf<<<(n + 255) / 256, blk, 0, stream>>>(rp, n, bsum, rf);
    k_scatter<<<(nnz + 255) / 256, blk, 0, stream>>>(rows, cols, vals, rf,
            colp, valp, nnz, scale);
}

extern "C" void kernel_launch(void* const* d_in, const int* in_sizes, int n_in,
                              void* d_out, int out_size, void* d_ws, size_t ws_size,
                              hipStream_t stream)
{
    const float* X0  = (const float*)d_in[0];
    const int*  eidx = (const int*)  d_in[1];
    const int*  tidx = (const int*)  d_in[2];
    const int* L0r = (const int*)d_in[3];
    const int* L0c = (const int*)d_in[4];
    const float* L0v = (const float*)d_in[5];
    const int* L1r = (const int*)d_in[6];
    const int* L1c = (const int*)d_in[7];
    const float* L1v = (const float*)d_in[8];
    const int* L2r = (const int*)d_in[9];
    const int* L2c = (const int*)d_in[10];
    const float* L2v = (const float*)d_in[11];
    const int* B1r = (const int*)d_in[12];
    const int* B1c = (const int*)d_in[13];
    const float* B1v = (const float*)d_in[14];
    const int* B2r = (const int*)d_in[15];
    const int* B2c = (const int*)d_in[16];
    const float* B2v = (const float*)d_in[17];
    const float* Wn   = (const float*)d_in[18];
    const float* bn   = (const float*)d_in[19];
    const float* We   = (const float*)d_in[20];
    const float* be   = (const float*)d_in[21];
    const float* Wt   = (const float*)d_in[22];
    const float* bt   = (const float*)d_in[23];
    const float* Wtri = (const float*)d_in[24];
    const float* btri = (const float*)d_in[25];
    const float* pw   = (const float*)d_in[26];

    const int N0 = in_sizes[0] / 128;
    const int N1 = in_sizes[1] / 2;
    const int N2 = in_sizes[2] / 3;
    const int nnz0 = in_sizes[3], nnz1 = in_sizes[6], nnz2 = in_sizes[9];
    const int nnzb1 = in_sizes[12], nnzb2 = in_sizes[15];

    // --- base workspace: S1 | S2 | Ts = 256,000,000 B exactly ---
    char* ws = (char*)d_ws;
    size_t off = 0;
    auto take = [&](size_t bytes) {
        void* p = ws + off;
        off += (bytes + 255) & ~(size_t)255;
        return p;
    };
    float* S1 = (float*)take((size_t)N1 * 512);
    float* S2 = (float*)take((size_t)N2 * 512);
    float* Ts = (float*)take((size_t)N1 * 512);

    auto align256 = [](size_t x) { return (x + 255) & ~(size_t)255; };

    // bit tables overlay Ts head (die when fused CSR-GEMM writes Ts)
    ulonglong2* Xb = (ulonglong2*)Ts;
    ulonglong2* Eb = (ulonglong2*)((char*)Ts + align256((size_t)N0 * 16));
    ulonglong2* Tb = (ulonglong2*)((char*)Eb + align256((size_t)N1 * 16));

    // d_out overlay: CSR-L1 | CSR-L2 | CSR-B2 | W splits | bsumA  (25.0 MB)
    char* dob = (char*)d_out;
    size_t doff = 0;
    int*   rpL1   = (int*)(dob + doff); doff += align256((size_t)(N1 + 1) * 4);
    int*   rfL1   = (int*)(dob + doff); doff += align256((size_t)(N1 + 1) * 4);
    int*   colpL1 = (int*)(dob + doff); doff += align256((size_t)nnz1 * 4);
    float* valpL1 = (float*)(dob + doff); doff += align256((size_t)nnz1 * 4);
    int*   rpL2   = (int*)(dob + doff); doff += align256((size_t)(N2 + 1) * 4);
    int*   rfL2   = (int*)(dob + doff); doff += align256((size_t)(N2 + 1) * 4);
    int*   colpL2 = (int*)(dob + doff); doff += align256((size_t)nnz2 * 4);
    float* valpL2 = (float*)(dob + doff); doff += align256((size_t)nnz2 * 4);
    int*   rpB2   = (int*)(dob + doff); doff += align256((size_t)(N1 + 1) * 4);
    int*   rfB2   = (int*)(dob + doff); doff += align256((size_t)(N1 + 1) * 4);
    int*   colpB2 = (int*)(dob + doff); doff += align256((size_t)nnzb2 * 4);
    float* valpB2 = (float*)(dob + doff); doff += align256((size_t)nnzb2 * 4);
    short* WThi  = (short*)(dob + doff); doff += 32768;
    short* WTlo  = (short*)(dob + doff); doff += 32768;
    short* WEhi  = (short*)(dob + doff); doff += 32768;
    short* WElo  = (short*)(dob + doff); doff += 32768;
    short* WRhi  = (short*)(dob + doff); doff += 32768;
    short* WRlo  = (short*)(dob + doff); doff += 32768;
    int*   bsumA = (int*)(dob + doff); doff += 1024;

    // S1-region overlay for phase B (after fused CSR-GEMM consumes H1)
    char* s1b = (char*)S1;
    size_t soff = 0;
    ulonglong2* Xb2 = (ulonglong2*)(s1b + soff); soff += align256((size_t)N0 * 16);
    int*   rpL0   = (int*)(s1b + soff); soff += align256((size_t)(N0 + 1) * 4);
    int*   rfL0   = (int*)(s1b + soff); soff += align256((size_t)(N0 + 1) * 4);
    int*   colpL0 = (int*)(s1b + soff); soff += align256((size_t)nnz0 * 4);
    float* valpL0 = (float*)(s1b + soff); soff += align256((size_t)nnz0 * 4);
    int*   rpB1   = (int*)(s1b + soff); soff += align256((size_t)(N0 + 1) * 4);
    int*   rfB1   = (int*)(s1b + soff); soff += align256((size_t)(N0 + 1) * 4);
    int*   colpB1 = (int*)(s1b + soff); soff += align256((size_t)nnzb1 * 4);
    float* valpB1 = (float*)(s1b + soff); soff += align256((size_t)nnzb1 * 4);
    short* WNhi  = (short*)(s1b + soff); soff += 32768;
    short* WNlo  = (short*)(s1b + soff); soff += 32768;
    int*   bsumB = (int*)(s1b + soff); soff += 1024;

    dim3 blk(256);
    dim3 blk512(512);

    // --- phase A: bit tables ---
    k_bits_node<<<(N0 + 3) / 4, blk, 0, stream>>>(X0, Xb, N0);
    k_bits_edge<<<(N1 + 255) / 256, blk, 0, stream>>>(eidx, Xb, Eb, N1);
    k_bits_tri<<<(N2 + 255) / 256, blk, 0, stream>>>(tidx, Xb, Tb, N2);

    // --- weight splits + CSR builds in d_out ---
    k_wsplit<<<64, blk, 0, stream>>>(Wt,   WThi, WTlo, 16384);
    k_wsplit<<<64, blk, 0, stream>>>(We,   WEhi, WElo, 16384);
    k_wsplit<<<64, blk, 0, stream>>>(Wtri, WRhi, WRlo, 16384);
    build_csr(L1r, L1c, L1v, rpL1, rfL1, colpL1, valpL1, bsumA, N1, nnz1, 1.0f, stream);
    build_csr(L2r, L2c, L2v, rpL2, rfL2, colpL2, valpL2, bsumA, N2, nnz2, 1.0f, stream);
    build_csr(B2r, B2c, B2v, rpB2, rfB2, colpB2, valpB2, bsumA, N1, nnzb2, 1.0f, stream);

    // --- FUSED: H2 = prelu((L2 @ X2f) @ Wt^T + bt)  -> S2 region ---
    k_fused_bin_gemm<<<(N2 + 127) / 128, blk512, 0, stream>>>(rpL2, colpL2, valpL2,
            Tb, WThi, WTlo, bt, pw, S2, N2, 1.0f);
    // --- FUSED: H1 = prelu((L1 @ X1f) @ We^T + be)  -> S1 region ---
    k_fused_bin_gemm<<<(N1 + 127) / 128, blk512, 0, stream>>>(rpL1, colpL1, valpL1,
            Eb, WEhi, WElo, be, pw, S1, N1, 1.0f);

    // --- FUSED: U = (B2 @ H2) @ Wtri^T + btri + H1  -> Ts
    //     (clobbers bit tables; consumes H1; replaces gather_write + U-GEMM) ---
    k_fused_csr_gemm<<<(N1 + 127) / 128, blk512, 0, stream>>>(rpB2, colpB2, valpB2,
            S2, WRhi, WRlo, btri, S1, Ts, N1);

    // --- phase B in S1 region: node bits + CSR-L0 + CSR-B1 + Wn split ---
    k_bits_node<<<(N0 + 3) / 4, blk, 0, stream>>>(X0, Xb2, N0);
    k_wsplit<<<64, blk, 0, stream>>>(Wn, WNhi, WNlo, 16384);
    build_csr(L0r, L0c, L0v, rpL0, rfL0, colpL0, valpL0, bsumB, N0, nnz0, 1.0f, stream);
    build_csr(B1r, B1c, B1v, rpB1, rfB1, colpB1, valpB1, bsumB, N0, nnzb1, 1.0f / 3.0f, stream);

    // --- FUSED: d_out = prelu((L0 @ X0b) @ Wn^T + bn)/3 (d_out scratch dead) ---
    k_fused_bin_gemm<<<(N0 + 127) / 128, blk512, 0, stream>>>(rpL0, colpL0, valpL0,
            Xb2, WNhi, WNlo, bn, pw, (float*)d_out, N0, 1.0f / 3.0f);
    // --- d_out += B1 @ U (valp pre-scaled 1/3; non-atomic) ---
    k_gather_add<<<(N0 + 3) / 4, blk, 0, stream>>>(rpB1, colpB1, valpB1, Ts,
            (float*)d_out, N0);
}